// Round 12
// baseline (120.349 us; speedup 1.0000x reference)
//
#include <hip/hip_runtime.h>

typedef unsigned short u16;
typedef unsigned int u32;
typedef __bf16 bf16x8 __attribute__((ext_vector_type(8)));
typedef float f32x4 __attribute__((ext_vector_type(4)));

__device__ __forceinline__ float bf2f(u16 v) {
    union { u32 u; float f; } c; c.u = ((u32)v) << 16; return c.f;
}
__device__ __forceinline__ u16 f2bf(float f) {
    union { float f; u32 u; } c; c.f = f;
    u32 u = c.u + 0x7fffu + ((c.u >> 16) & 1u);   // RNE
    return (u16)(u >> 16);
}

// ---------------- K1: fused cond_scale (blocks 0..255) + rms_inv (blocks 256..767)
__global__ __launch_bounds__(256) void setup_kernel(
    const float* __restrict__ cond, const float* __restrict__ w_cond,
    const float* __restrict__ x, float* __restrict__ ns, float* __restrict__ inv)
{
    int lane = threadIdx.x & 63;
    int b = blockIdx.x;
    if (b < 256) {
        int wid = b * 4 + (threadIdx.x >> 6); // 0..1023
        int n = wid >> 9, c = wid & 511;
        const float* cp = cond + n * 768;
        const float* wp = w_cond + (size_t)c * 768;
        float s = 0.f;
        #pragma unroll
        for (int j = 0; j < 12; j++)
            s += cp[lane + j * 64] * wp[lane + j * 64];
        #pragma unroll
        for (int d = 1; d < 64; d <<= 1) s += __shfl_xor(s, d);
        if (lane == 0) ns[wid] = s + 1.f;
    } else {
        int p = (b - 256) * 4 + (threadIdx.x >> 6); // 0..2047
        const float* xp = x + (size_t)p * 512;
        float s = 0.f;
        #pragma unroll
        for (int j = 0; j < 8; j++) { float v = xp[lane + j * 64]; s += v * v; }
        #pragma unroll
        for (int d = 1; d < 64; d <<= 1) s += __shfl_xor(s, d);
        if (lane == 0) inv[p] = rsqrtf(s * (1.f / 512.f) + 1e-6f);
    }
}

// ---------------- K2: bf16 conversions. blocks 0..1023: xn = rmsnorm(x)*ns (fused);
// blocks 1024..1791: w_qkv -> bf16 ; blocks 1792..2047: w_out -> bf16
__global__ __launch_bounds__(256) void convert_kernel(
    const float* __restrict__ x, const float* __restrict__ ns, const float* __restrict__ inv,
    const float* __restrict__ w_qkv, const float* __restrict__ w_out,
    u16* __restrict__ xn, u16* __restrict__ wqkvb, u16* __restrict__ woutb)
{
    int b = blockIdx.x;
    const float* src; u16* dst; size_t i4;
    bool rms = false;
    if (b < 1024)      { src = x;     dst = xn;    i4 = (size_t)(b)        * 1024 + threadIdx.x * 4; rms = true; }
    else if (b < 1792) { src = w_qkv; dst = wqkvb; i4 = (size_t)(b - 1024) * 1024 + threadIdx.x * 4; }
    else               { src = w_out; dst = woutb; i4 = (size_t)(b - 1792) * 1024 + threadIdx.x * 4; }
    float4 v = *(const float4*)(src + i4);
    if (rms) {
        int p = (int)(i4 >> 9), c = (int)(i4 & 511);
        float iv = inv[p];
        float4 nv = *(const float4*)(ns + (p >> 10) * 512 + c);
        v.x *= nv.x * iv; v.y *= nv.y * iv; v.z *= nv.z * iv; v.w *= nv.w * iv;
    }
    ushort4 o; o.x = f2bf(v.x); o.y = f2bf(v.y); o.z = f2bf(v.z); o.w = f2bf(v.w);
    *(ushort4*)(dst + i4) = o;
}

// ---------------- K3: qkv GEMM, 128x128 block tile, fused q/k norm + RoPE epilogue.
// Grid (16,12). Block = 4 waves in 2x2; wave (wm,wn) owns 64x64 quadrant:
// rows bm+wm*64+[0,64), cols bn+wn*64+[0,64) = ONE (qk,head) slice -> norm is
// wave-local (sum over ci + 16-lane butterfly); RoPE pair (d,d+16) = ci 0<->1.
// A-frag: m=lane&15, k=quad*8+j ; C/D: col=ci*16+m, row=ri*16+quad*4+reg [m89/m91]
__global__ __launch_bounds__(256) void gemm_qkv(
    const u16* __restrict__ A, const u16* __restrict__ B,
    const float* __restrict__ pos, const float* __restrict__ scale,
    u16* __restrict__ qp, u16* __restrict__ kp, u16* __restrict__ vp)
{
    __shared__ __align__(16) u16 As[128][40];
    __shared__ __align__(16) u16 Bs[128][40];
    int tid = threadIdx.x;
    int lane = tid & 63;
    int w = tid >> 6;
    int wm = w >> 1, wn = w & 1;
    int bm = blockIdx.x * 128, bn = blockIdx.y * 128;
    int s = blockIdx.y * 2 + wn;        // this wave's slice
    int qk = s >> 3, h = s & 7;
    int lrow = tid >> 1, cg = (tid & 1) * 16;

    f32x4 acc[4][4];
    #pragma unroll
    for (int ri = 0; ri < 4; ri++)
    #pragma unroll
    for (int ci = 0; ci < 4; ci++) { f32x4 z = {0.f,0.f,0.f,0.f}; acc[ri][ci] = z; }

    const u16* Ap = A + (size_t)(bm + lrow) * 512 + cg;
    const u16* Bp = B + (size_t)(bn + lrow) * 512 + cg;
    int m = lane & 15, quad = lane >> 4, kq = quad * 8;

    for (int k0 = 0; k0 < 512; k0 += 32) {
        uint4 a0 = *(const uint4*)(Ap + k0);
        uint4 a1 = *(const uint4*)(Ap + k0 + 8);
        uint4 b0 = *(const uint4*)(Bp + k0);
        uint4 b1 = *(const uint4*)(Bp + k0 + 8);
        *(uint4*)&As[lrow][cg]     = a0;
        *(uint4*)&As[lrow][cg + 8] = a1;
        *(uint4*)&Bs[lrow][cg]     = b0;
        *(uint4*)&Bs[lrow][cg + 8] = b1;
        __syncthreads();
        #pragma unroll
        for (int ri = 0; ri < 4; ri++) {
            bf16x8 af = *(const bf16x8*)&As[wm * 64 + ri * 16 + m][kq];
            #pragma unroll
            for (int ci = 0; ci < 4; ci++) {
                bf16x8 bfr = *(const bf16x8*)&Bs[wn * 64 + ci * 16 + m][kq];
                acc[ri][ci] = __builtin_amdgcn_mfma_f32_16x16x32_bf16(af, bfr, acc[ri][ci], 0, 0, 0);
            }
        }
        __syncthreads();
    }

    // ---- epilogue (wave-local): head-norm + RoPE for q/k; passthrough v
    u16* plane = (qk == 0) ? qp : (qk == 1) ? kp : vp;
    float sq = (qk < 2) ? sqrtf(scale[h]) : 0.f;
    // freqs[h][t] = pi * 10^((t*8+h)/128), t = m
    float fr = 3.14159265358979323846f * expf((float)(m * 8 + h) * (2.302585092994046f / 128.f));
    #pragma unroll
    for (int ri = 0; ri < 4; ri++) {
        float invn[4];
        if (qk < 2) {
            #pragma unroll
            for (int reg = 0; reg < 4; reg++) {
                float pa = acc[ri][0][reg] * acc[ri][0][reg]
                         + acc[ri][1][reg] * acc[ri][1][reg]
                         + acc[ri][2][reg] * acc[ri][2][reg]
                         + acc[ri][3][reg] * acc[ri][3][reg];
                #pragma unroll
                for (int d = 1; d < 16; d <<= 1) pa += __shfl_xor(pa, d);
                invn[reg] = sq * rsqrtf(pa + 1e-6f);
            }
        }
        #pragma unroll
        for (int reg = 0; reg < 4; reg++) {
            int p = bm + wm * 64 + ri * 16 + quad * 4 + reg;
            size_t basep = ((size_t)((p >> 10) * 8 + h) * 1024 + (p & 1023)) * 64;
            float v0 = acc[ri][0][reg], v1 = acc[ri][1][reg];
            float v2 = acc[ri][2][reg], v3 = acc[ri][3][reg];
            if (qk < 2) {
                float ivn = invn[reg];
                v0 *= ivn; v1 *= ivn; v2 *= ivn; v3 *= ivn;
                float th = pos[p] * fr;
                float cs = cosf(th), sn = sinf(th);
                float o0 = v0 * cs - v1 * sn;
                float o1 = v1 * cs + v0 * sn;
                v0 = o0; v1 = o1;
            }
            plane[basep + m]      = f2bf(v0);
            plane[basep + 16 + m] = f2bf(v1);
            plane[basep + 32 + m] = f2bf(v2);
            plane[basep + 48 + m] = f2bf(v3);
        }
    }
}

// ---------------- MFMA GEMM (out proj): C[M][N] fp32 = A @ B^T + skip
__global__ __launch_bounds__(256) void gemm_out(
    const u16* __restrict__ A, const u16* __restrict__ B,
    float* __restrict__ C, const float* __restrict__ skip, int N, int K)
{
    __shared__ __align__(16) u16 As[64][40];
    __shared__ __align__(16) u16 Bs[64][40];
    int tid = threadIdx.x;
    int lane = tid & 63;
    int w = tid >> 6;
    int wm = w >> 1, wn = w & 1;
    int bm = blockIdx.x * 64, bn = blockIdx.y * 64;
    int lrow = tid >> 2, lc8 = (tid & 3) * 8;

    f32x4 zero = {0.f, 0.f, 0.f, 0.f};
    f32x4 acc[2][2];
    acc[0][0] = zero; acc[0][1] = zero; acc[1][0] = zero; acc[1][1] = zero;

    const u16* Ap = A + (size_t)(bm + lrow) * K + lc8;
    const u16* Bp = B + (size_t)(bn + lrow) * K + lc8;
    int r = lane & 15, kq = (lane >> 4) * 8;

    for (int k0 = 0; k0 < K; k0 += 32) {
        *(uint4*)&As[lrow][lc8] = *(const uint4*)(Ap + k0);
        *(uint4*)&Bs[lrow][lc8] = *(const uint4*)(Bp + k0);
        __syncthreads();
        #pragma unroll
        for (int ri = 0; ri < 2; ri++) {
            bf16x8 af = *(const bf16x8*)&As[wm * 32 + ri * 16 + r][kq];
            #pragma unroll
            for (int ci = 0; ci < 2; ci++) {
                bf16x8 bfr = *(const bf16x8*)&Bs[wn * 32 + ci * 16 + r][kq];
                acc[ri][ci] = __builtin_amdgcn_mfma_f32_16x16x32_bf16(af, bfr, acc[ri][ci], 0, 0, 0);
            }
        }
        __syncthreads();
    }

    #pragma unroll
    for (int ri = 0; ri < 2; ri++)
    #pragma unroll
    for (int ci = 0; ci < 2; ci++) {
        int col = bn + wn * 32 + ci * 16 + (lane & 15);
        int row0 = bm + wm * 32 + ri * 16 + (lane >> 4) * 4;
        #pragma unroll
        for (int reg = 0; reg < 4; reg++) {
            size_t idx = (size_t)(row0 + reg) * N + col;
            C[idx] = acc[ri][ci][reg] + skip[idx];
        }
    }
}

// ---------------- K5: MFMA neighborhood attention.
// One block per (n, h, 8x8 query tile). Union of neighborhoods = 14x14 = 196 keys.
__global__ __launch_bounds__(256) void attn_mfma(
    const u16* __restrict__ qp, const u16* __restrict__ kp, const u16* __restrict__ vp,
    u16* __restrict__ ob)
{
    __shared__ __align__(16) u16 Kb[208 * 72];   // K:[nb][64] stride 72; reused as Vt:[64][224] stride 234
    __shared__ __align__(16) u16 Sb[64 * 232];   // S fp16 then P bf16, row stride 232

    int tid = threadIdx.x, lane = tid & 63, w = tid >> 6;
    int bx = blockIdx.x;
    int n = bx >> 7, h = (bx >> 4) & 7, t = bx & 15;
    int ti = (t >> 2) * 8, tj = (t & 3) * 8;
    int r0 = min(max(ti - 3, 0), 18), c0 = min(max(tj - 3, 0), 18);
    const u16* qpl = qp + ((size_t)(n * 8 + h) << 16);
    const u16* kpl = kp + ((size_t)(n * 8 + h) << 16);
    const u16* vpl = vp + ((size_t)(n * 8 + h) << 16);

    for (int g = tid; g < 1568; g += 256) {
        int nb = g >> 3, k8 = (g & 7) << 3;
        int ar = nb / 14, ac = nb - ar * 14;
        *(uint4*)&Kb[nb * 72 + k8] =
            *(const uint4*)&kpl[(size_t)((r0 + ar) * 32 + c0 + ac) * 64 + k8];
    }
    __syncthreads();

    int m = lane & 15, quad = lane >> 4;
    {
        int r = w * 16 + m;
        int tok = (ti + (r >> 3)) * 32 + (tj + (r & 7));
        bf16x8 qf0 = *(const bf16x8*)&qpl[(size_t)tok * 64 + quad * 8];
        bf16x8 qf1 = *(const bf16x8*)&qpl[(size_t)tok * 64 + 32 + quad * 8];
        _Float16* sp = (_Float16*)Sb;
        #pragma unroll
        for (int nt = 0; nt < 13; nt++) {
            f32x4 acc = {0.f, 0.f, 0.f, 0.f};
            bf16x8 b0 = *(const bf16x8*)&Kb[(nt * 16 + m) * 72 + quad * 8];
            bf16x8 b1 = *(const bf16x8*)&Kb[(nt * 16 + m) * 72 + 32 + quad * 8];
            acc = __builtin_amdgcn_mfma_f32_16x16x32_bf16(qf0, b0, acc, 0, 0, 0);
            acc = __builtin_amdgcn_mfma_f32_16x16x32_bf16(qf1, b1, acc, 0, 0, 0);
            #pragma unroll
            for (int reg = 0; reg < 4; reg++)
                sp[(w * 16 + quad * 4 + reg) * 232 + nt * 16 + m] = (_Float16)acc[reg];
        }
    }
    __syncthreads();

    for (int g = tid; g < 1568; g += 256) {
        int nb = g >> 3, k8 = (g & 7) << 3;
        int ar = nb / 14, ac = nb - ar * 14;
        uint4 v4 = *(const uint4*)&vpl[(size_t)((r0 + ar) * 32 + c0 + ac) * 64 + k8];
        u32 uu[4] = {v4.x, v4.y, v4.z, v4.w};
        #pragma unroll
        for (int e = 0; e < 4; e++) {
            Kb[(k8 + 2 * e) * 234 + nb]     = (u16)(uu[e] & 0xffff);
            Kb[(k8 + 2 * e + 1) * 234 + nb] = (u16)(uu[e] >> 16);
        }
    }
    for (int g = tid; g < 1792; g += 256) {
        int d = g / 28, nb = 196 + (g - d * 28);
        Kb[d * 234 + nb] = 0;
    }

    {
        int l16 = lane & 15, g4 = lane >> 4;
        #pragma unroll
        for (int it = 0; it < 4; it++) {
            int rr = w * 16 + it * 4 + g4;
            int i2 = ti + (rr >> 3), j2 = tj + (rr & 7);
            int alo = min(max(i2 - 3, 0), 25) - r0;
            int blo = min(max(j2 - 3, 0), 25) - c0;
            const _Float16* sp = (const _Float16*)&Sb[rr * 232];
            float vals[14];
            float mx = -1e30f;
            #pragma unroll
            for (int c = 0; c < 14; c++) {
                int col = l16 + c * 16;
                float v = -1e30f;
                if (col < 196) {
                    int ar = col / 14, ac = col - ar * 14;
                    if (ar >= alo && ar < alo + 7 && ac >= blo && ac < blo + 7)
                        v = (float)sp[col];
                }
                vals[c] = v; mx = fmaxf(mx, v);
            }
            #pragma unroll
            for (int d = 1; d < 16; d <<= 1) mx = fmaxf(mx, __shfl_xor(mx, d));
            float s = 0.f;
            #pragma unroll
            for (int c = 0; c < 14; c++) {
                float e = (vals[c] > -1e29f) ? expf(vals[c] - mx) : 0.f;
                vals[c] = e; s += e;
            }
            #pragma unroll
            for (int d = 1; d < 16; d <<= 1) s += __shfl_xor(s, d);
            float rs = __frcp_rn(s);
            u16* pp = &Sb[rr * 232];
            #pragma unroll
            for (int c = 0; c < 14; c++)
                pp[l16 + c * 16] = f2bf(vals[c] * rs);
        }
    }
    __syncthreads();

    f32x4 oacc[4];
    #pragma unroll
    for (int nt = 0; nt < 4; nt++) { f32x4 z = {0.f,0.f,0.f,0.f}; oacc[nt] = z; }
    #pragma unroll
    for (int ks = 0; ks < 7; ks++) {
        bf16x8 pa = *(const bf16x8*)&Sb[(w * 16 + m) * 232 + ks * 32 + quad * 8];
        #pragma unroll
        for (int nt = 0; nt < 4; nt++) {
            int ad = (nt * 16 + m) * 234 + ks * 32 + quad * 8;
            union { u32 u[4]; bf16x8 v; } vb;
            vb.u[0] = *(const u32*)&Kb[ad];
            vb.u[1] = *(const u32*)&Kb[ad + 2];
            vb.u[2] = *(const u32*)&Kb[ad + 4];
            vb.u[3] = *(const u32*)&Kb[ad + 6];
            oacc[nt] = __builtin_amdgcn_mfma_f32_16x16x32_bf16(pa, vb.v, oacc[nt], 0, 0, 0);
        }
    }
    #pragma unroll
    for (int nt = 0; nt < 4; nt++) {
        #pragma unroll
        for (int reg = 0; reg < 4; reg++) {
            int rr = w * 16 + quad * 4 + reg;
            int tok = (ti + (rr >> 3)) * 32 + (tj + (rr & 7));
            ob[(size_t)(n * 1024 + tok) * 512 + h * 64 + nt * 16 + m] = f2bf(oacc[nt][reg]);
        }
    }
}

extern "C" void kernel_launch(void* const* d_in, const int* in_sizes, int n_in,
                              void* d_out, int out_size, void* d_ws, size_t ws_size,
                              hipStream_t stream)
{
    // Match inputs by unique element count (robust to ordering).
    const float *x = nullptr, *pos = nullptr, *cond = nullptr, *w_cond = nullptr,
                *w_qkv = nullptr, *scale = nullptr, *w_out = nullptr;
    for (int i = 0; i < n_in; i++) {
        switch (in_sizes[i]) {
            case 1048576: x      = (const float*)d_in[i]; break;  // 2*32*32*512
            case 2048:    pos    = (const float*)d_in[i]; break;  // 2*32*32*1
            case 1536:    cond   = (const float*)d_in[i]; break;  // 2*768
            case 393216:  w_cond = (const float*)d_in[i]; break;  // 512*768
            case 786432:  w_qkv  = (const float*)d_in[i]; break;  // 1536*512
            case 8:       scale  = (const float*)d_in[i]; break;  // 8
            case 262144:  w_out  = (const float*)d_in[i]; break;  // 512*512
            default: break;
        }
    }
    float* out = (float*)d_out;   // FLOAT32 output

    // ws: ns 4K | inv 8K | xn 2M | wqkvb 1.5M | woutb .5M | qp/kp/vp 2M each | ob 2M
    char* ws = (char*)d_ws;
    float* ns    = (float*)ws;                          // [2][512]
    float* inv   = (float*)(ws + 4096);                 // [2048]
    u16*   xn    = (u16*)(ws + 12288);                  // [2048][512]  bf16
    u16*   wqkvb = (u16*)(ws + 12288 + 2097152);        // [1536][512]  bf16
    u16*   woutb = (u16*)(ws + 12288 + 3670016);        // [512][512]   bf16
    u16*   qp    = (u16*)(ws + 12288 + 4194304);        // [2][8][1024][64] bf16
    u16*   kp    = (u16*)(ws + 12288 + 6291456);        // same
    u16*   vp    = (u16*)(ws + 12288 + 8388608);        // same
    u16*   ob    = (u16*)(ws + 12288 + 10485760);       // [2048][512]  bf16

    setup_kernel<<<768, 256, 0, stream>>>(cond, w_cond, x, ns, inv);
    convert_kernel<<<2048, 256, 0, stream>>>(x, ns, inv, w_qkv, w_out, xn, wqkvb, woutb);
    gemm_qkv<<<dim3(16, 12), 256, 0, stream>>>(xn, wqkvb, pos, scale, qp, kp, vp);
    attn_mfma<<<256, 256, 0, stream>>>(qp, kp, vp, ob);
    gemm_out<<<dim3(32, 8), 256, 0, stream>>>(ob, woutb, out, x, 512, 512);
}

// Round 13
// 117.519 us; speedup vs baseline: 1.0241x; 1.0241x over previous
//
#include <hip/hip_runtime.h>

typedef unsigned short u16;
typedef unsigned int u32;
typedef __bf16 bf16x8 __attribute__((ext_vector_type(8)));
typedef float f32x4 __attribute__((ext_vector_type(4)));

__device__ __forceinline__ float bf2f(u16 v) {
    union { u32 u; float f; } c; c.u = ((u32)v) << 16; return c.f;
}
__device__ __forceinline__ u16 f2bf(float f) {
    union { float f; u32 u; } c; c.f = f;
    u32 u = c.u + 0x7fffu + ((c.u >> 16) & 1u);   // RNE
    return (u16)(u >> 16);
}

// ---------------- K1 (merged): blocks 0..255 cond_scale | 256..767 rms_inv |
//                  768..1535 w_qkv->bf16 | 1536..1791 w_out->bf16   (all independent)
__global__ __launch_bounds__(256) void setup_kernel(
    const float* __restrict__ cond, const float* __restrict__ w_cond,
    const float* __restrict__ x, const float* __restrict__ w_qkv,
    const float* __restrict__ w_out,
    float* __restrict__ ns, float* __restrict__ inv,
    u16* __restrict__ wqkvb, u16* __restrict__ woutb)
{
    int b = blockIdx.x;
    if (b < 768) {
        int lane = threadIdx.x & 63;
        if (b < 256) {
            int wid = b * 4 + (threadIdx.x >> 6); // 0..1023
            int n = wid >> 9, c = wid & 511;
            const float* cp = cond + n * 768;
            const float* wp = w_cond + (size_t)c * 768;
            float s = 0.f;
            #pragma unroll
            for (int j = 0; j < 12; j++)
                s += cp[lane + j * 64] * wp[lane + j * 64];
            #pragma unroll
            for (int d = 1; d < 64; d <<= 1) s += __shfl_xor(s, d);
            if (lane == 0) ns[wid] = s + 1.f;
        } else {
            int p = (b - 256) * 4 + (threadIdx.x >> 6); // 0..2047
            const float* xp = x + (size_t)p * 512;
            float s = 0.f;
            #pragma unroll
            for (int j = 0; j < 8; j++) { float v = xp[lane + j * 64]; s += v * v; }
            #pragma unroll
            for (int d = 1; d < 64; d <<= 1) s += __shfl_xor(s, d);
            if (lane == 0) inv[p] = rsqrtf(s * (1.f / 512.f) + 1e-6f);
        }
    } else {
        const float* src; u16* dst; size_t i4;
        if (b < 1536) { src = w_qkv; dst = wqkvb; i4 = (size_t)(b - 768)  * 1024 + threadIdx.x * 4; }
        else          { src = w_out; dst = woutb; i4 = (size_t)(b - 1536) * 1024 + threadIdx.x * 4; }
        float4 v = *(const float4*)(src + i4);
        ushort4 o; o.x = f2bf(v.x); o.y = f2bf(v.y); o.z = f2bf(v.z); o.w = f2bf(v.w);
        *(ushort4*)(dst + i4) = o;
    }
}

// ---------------- K2: qkv GEMM, 64x64 tile, RMS-norm fused in A-staging,
// q/k head-norm + RoPE fused in epilogue. Writes head-major bf16 planes.
// Block (bx,by): rows bx*64 tokens, cols = one (qk,head) slice (by: 0..7 q / 8..15 k / 16..23 v).
// A-frag: m=lane&15, k=quad*8+j ; C/D: col=ci*16+m (within wn half), row=(quad*4+reg) [m89/m91]
// RoPE pair (d, d+16), d<16: ci=0/ci=1 of wn==0 wave -> register-local rotation.
__global__ __launch_bounds__(256) void gemm_qkv(
    const float* __restrict__ x, const float* __restrict__ ns, const float* __restrict__ inv,
    const u16* __restrict__ B,
    const float* __restrict__ pos, const float* __restrict__ scale,
    u16* __restrict__ qp, u16* __restrict__ kp, u16* __restrict__ vp)
{
    __shared__ __align__(16) u16 As[64][40];
    __shared__ __align__(16) u16 Bs[64][40];
    int tid = threadIdx.x;
    int lane = tid & 63;
    int w = tid >> 6;
    int wm = w >> 1, wn = w & 1;
    int bm = blockIdx.x * 64, bn = blockIdx.y * 64;
    int qk = blockIdx.y >> 3, h = blockIdx.y & 7;
    int lrow = tid >> 2, lc8 = (tid & 3) * 8;

    f32x4 zero = {0.f, 0.f, 0.f, 0.f};
    f32x4 acc[2][2];
    acc[0][0] = zero; acc[0][1] = zero; acc[1][0] = zero; acc[1][1] = zero;

    int tr = bm + lrow;
    float iv = inv[tr];
    const float* Ax  = x  + (size_t)tr * 512 + lc8;
    const float* nsr = ns + (tr >> 10) * 512 + lc8;
    const u16*   Bp  = B  + (size_t)(bn + lrow) * 512 + lc8;
    int m = lane & 15, quad = lane >> 4, kq = quad * 8;

    for (int k0 = 0; k0 < 512; k0 += 32) {
        float4 a0 = *(const float4*)(Ax + k0);
        float4 a1 = *(const float4*)(Ax + k0 + 4);
        float4 n0 = *(const float4*)(nsr + k0);
        float4 n1 = *(const float4*)(nsr + k0 + 4);
        uint4 ap;
        ap.x = (u32)f2bf(a0.x * n0.x * iv) | ((u32)f2bf(a0.y * n0.y * iv) << 16);
        ap.y = (u32)f2bf(a0.z * n0.z * iv) | ((u32)f2bf(a0.w * n0.w * iv) << 16);
        ap.z = (u32)f2bf(a1.x * n1.x * iv) | ((u32)f2bf(a1.y * n1.y * iv) << 16);
        ap.w = (u32)f2bf(a1.z * n1.z * iv) | ((u32)f2bf(a1.w * n1.w * iv) << 16);
        *(uint4*)&As[lrow][lc8] = ap;
        *(uint4*)&Bs[lrow][lc8] = *(const uint4*)(Bp + k0);
        __syncthreads();
        #pragma unroll
        for (int ri = 0; ri < 2; ri++) {
            bf16x8 af = *(const bf16x8*)&As[wm * 32 + ri * 16 + m][kq];
            #pragma unroll
            for (int ci = 0; ci < 2; ci++) {
                bf16x8 bfr = *(const bf16x8*)&Bs[wn * 32 + ci * 16 + m][kq];
                acc[ri][ci] = __builtin_amdgcn_mfma_f32_16x16x32_bf16(af, bfr, acc[ri][ci], 0, 0, 0);
            }
        }
        __syncthreads();
    }

    // ---- epilogue: head-norm (sum over 64 cols via cross-wave LDS) + RoPE for q/k
    float invn[2][4];
    if (qk < 2) {
        float* red = (float*)As;   // [64][2] partials, reuse LDS
        #pragma unroll
        for (int ri = 0; ri < 2; ri++)
        #pragma unroll
        for (int reg = 0; reg < 4; reg++) {
            float pa = acc[ri][0][reg] * acc[ri][0][reg]
                     + acc[ri][1][reg] * acc[ri][1][reg];
            #pragma unroll
            for (int d = 1; d < 16; d <<= 1) pa += __shfl_xor(pa, d);
            if (m == 0) red[(wm * 32 + ri * 16 + quad * 4 + reg) * 2 + wn] = pa;
        }
        __syncthreads();
        float sq = sqrtf(scale[h]);
        #pragma unroll
        for (int ri = 0; ri < 2; ri++)
        #pragma unroll
        for (int reg = 0; reg < 4; reg++) {
            int rl = wm * 32 + ri * 16 + quad * 4 + reg;
            invn[ri][reg] = sq * rsqrtf(red[rl * 2] + red[rl * 2 + 1] + 1e-6f);
        }
    }
    u16* plane = (qk == 0) ? qp : (qk == 1) ? kp : vp;
    // freqs[h][t] = pi * 10^((t*8+h)/128), t = m
    float fr = 3.14159265358979323846f * expf((float)(m * 8 + h) * (2.302585092994046f / 128.f));
    #pragma unroll
    for (int ri = 0; ri < 2; ri++)
    #pragma unroll
    for (int reg = 0; reg < 4; reg++) {
        int rl = wm * 32 + ri * 16 + quad * 4 + reg;
        int p = bm + rl;
        size_t basep = ((size_t)((p >> 10) * 8 + h) * 1024 + (p & 1023)) * 64;
        float v0 = acc[ri][0][reg], v1 = acc[ri][1][reg];
        if (qk < 2) {
            float ivn = invn[ri][reg];
            v0 *= ivn; v1 *= ivn;
            if (wn == 0) {   // dims 0..31: rotate (d, d+16)
                float th = pos[p] * fr;
                float cs = cosf(th), sn = sinf(th);
                float o0 = v0 * cs - v1 * sn;
                float o1 = v1 * cs + v0 * sn;
                v0 = o0; v1 = o1;
            }
        }
        plane[basep + wn * 32 + m]      = f2bf(v0);
        plane[basep + wn * 32 + 16 + m] = f2bf(v1);
    }
}

// ---------------- MFMA GEMM (out proj): C[M][N] fp32 = A @ B^T + skip
__global__ __launch_bounds__(256) void gemm_out(
    const u16* __restrict__ A, const u16* __restrict__ B,
    float* __restrict__ C, const float* __restrict__ skip, int N, int K)
{
    __shared__ __align__(16) u16 As[64][40];
    __shared__ __align__(16) u16 Bs[64][40];
    int tid = threadIdx.x;
    int lane = tid & 63;
    int w = tid >> 6;
    int wm = w >> 1, wn = w & 1;
    int bm = blockIdx.x * 64, bn = blockIdx.y * 64;
    int lrow = tid >> 2, lc8 = (tid & 3) * 8;

    f32x4 zero = {0.f, 0.f, 0.f, 0.f};
    f32x4 acc[2][2];
    acc[0][0] = zero; acc[0][1] = zero; acc[1][0] = zero; acc[1][1] = zero;

    const u16* Ap = A + (size_t)(bm + lrow) * K + lc8;
    const u16* Bp = B + (size_t)(bn + lrow) * K + lc8;
    int r = lane & 15, kq = (lane >> 4) * 8;

    for (int k0 = 0; k0 < K; k0 += 32) {
        *(uint4*)&As[lrow][lc8] = *(const uint4*)(Ap + k0);
        *(uint4*)&Bs[lrow][lc8] = *(const uint4*)(Bp + k0);
        __syncthreads();
        #pragma unroll
        for (int ri = 0; ri < 2; ri++) {
            bf16x8 af = *(const bf16x8*)&As[wm * 32 + ri * 16 + r][kq];
            #pragma unroll
            for (int ci = 0; ci < 2; ci++) {
                bf16x8 bfr = *(const bf16x8*)&Bs[wn * 32 + ci * 16 + r][kq];
                acc[ri][ci] = __builtin_amdgcn_mfma_f32_16x16x32_bf16(af, bfr, acc[ri][ci], 0, 0, 0);
            }
        }
        __syncthreads();
    }

    #pragma unroll
    for (int ri = 0; ri < 2; ri++)
    #pragma unroll
    for (int ci = 0; ci < 2; ci++) {
        int col = bn + wn * 32 + ci * 16 + (lane & 15);
        int row0 = bm + wm * 32 + ri * 16 + (lane >> 4) * 4;
        #pragma unroll
        for (int reg = 0; reg < 4; reg++) {
            size_t idx = (size_t)(row0 + reg) * N + col;
            C[idx] = acc[ri][ci][reg] + skip[idx];
        }
    }
}

// ---------------- K5: MFMA neighborhood attention.
// One block per (n, h, 8x8 query tile). Union of neighborhoods = 14x14 = 196 keys.
__global__ __launch_bounds__(256) void attn_mfma(
    const u16* __restrict__ qp, const u16* __restrict__ kp, const u16* __restrict__ vp,
    u16* __restrict__ ob)
{
    __shared__ __align__(16) u16 Kb[208 * 72];   // K:[nb][64] stride 72; reused as Vt:[64][224] stride 234
    __shared__ __align__(16) u16 Sb[64 * 232];   // S fp16 then P bf16, row stride 232

    int tid = threadIdx.x, lane = tid & 63, w = tid >> 6;
    int bx = blockIdx.x;
    int n = bx >> 7, h = (bx >> 4) & 7, t = bx & 15;
    int ti = (t >> 2) * 8, tj = (t & 3) * 8;
    int r0 = min(max(ti - 3, 0), 18), c0 = min(max(tj - 3, 0), 18);
    const u16* qpl = qp + ((size_t)(n * 8 + h) << 16);
    const u16* kpl = kp + ((size_t)(n * 8 + h) << 16);
    const u16* vpl = vp + ((size_t)(n * 8 + h) << 16);

    for (int g = tid; g < 1568; g += 256) {
        int nb = g >> 3, k8 = (g & 7) << 3;
        int ar = nb / 14, ac = nb - ar * 14;
        *(uint4*)&Kb[nb * 72 + k8] =
            *(const uint4*)&kpl[(size_t)((r0 + ar) * 32 + c0 + ac) * 64 + k8];
    }
    __syncthreads();

    int m = lane & 15, quad = lane >> 4;
    {
        int r = w * 16 + m;
        int tok = (ti + (r >> 3)) * 32 + (tj + (r & 7));
        bf16x8 qf0 = *(const bf16x8*)&qpl[(size_t)tok * 64 + quad * 8];
        bf16x8 qf1 = *(const bf16x8*)&qpl[(size_t)tok * 64 + 32 + quad * 8];
        _Float16* sp = (_Float16*)Sb;
        #pragma unroll
        for (int nt = 0; nt < 13; nt++) {
            f32x4 acc = {0.f, 0.f, 0.f, 0.f};
            bf16x8 b0 = *(const bf16x8*)&Kb[(nt * 16 + m) * 72 + quad * 8];
            bf16x8 b1 = *(const bf16x8*)&Kb[(nt * 16 + m) * 72 + 32 + quad * 8];
            acc = __builtin_amdgcn_mfma_f32_16x16x32_bf16(qf0, b0, acc, 0, 0, 0);
            acc = __builtin_amdgcn_mfma_f32_16x16x32_bf16(qf1, b1, acc, 0, 0, 0);
            #pragma unroll
            for (int reg = 0; reg < 4; reg++)
                sp[(w * 16 + quad * 4 + reg) * 232 + nt * 16 + m] = (_Float16)acc[reg];
        }
    }
    __syncthreads();

    for (int g = tid; g < 1568; g += 256) {
        int nb = g >> 3, k8 = (g & 7) << 3;
        int ar = nb / 14, ac = nb - ar * 14;
        uint4 v4 = *(const uint4*)&vpl[(size_t)((r0 + ar) * 32 + c0 + ac) * 64 + k8];
        u32 uu[4] = {v4.x, v4.y, v4.z, v4.w};
        #pragma unroll
        for (int e = 0; e < 4; e++) {
            Kb[(k8 + 2 * e) * 234 + nb]     = (u16)(uu[e] & 0xffff);
            Kb[(k8 + 2 * e + 1) * 234 + nb] = (u16)(uu[e] >> 16);
        }
    }
    for (int g = tid; g < 1792; g += 256) {
        int d = g / 28, nb = 196 + (g - d * 28);
        Kb[d * 234 + nb] = 0;
    }

    {
        int l16 = lane & 15, g4 = lane >> 4;
        #pragma unroll
        for (int it = 0; it < 4; it++) {
            int rr = w * 16 + it * 4 + g4;
            int i2 = ti + (rr >> 3), j2 = tj + (rr & 7);
            int alo = min(max(i2 - 3, 0), 25) - r0;
            int blo = min(max(j2 - 3, 0), 25) - c0;
            const _Float16* sp = (const _Float16*)&Sb[rr * 232];
            float vals[14];
            float mx = -1e30f;
            #pragma unroll
            for (int c = 0; c < 14; c++) {
                int col = l16 + c * 16;
                float v = -1e30f;
                if (col < 196) {
                    int ar = col / 14, ac = col - ar * 14;
                    if (ar >= alo && ar < alo + 7 && ac >= blo && ac < blo + 7)
                        v = (float)sp[col];
                }
                vals[c] = v; mx = fmaxf(mx, v);
            }
            #pragma unroll
            for (int d = 1; d < 16; d <<= 1) mx = fmaxf(mx, __shfl_xor(mx, d));
            float s = 0.f;
            #pragma unroll
            for (int c = 0; c < 14; c++) {
                float e = (vals[c] > -1e29f) ? expf(vals[c] - mx) : 0.f;
                vals[c] = e; s += e;
            }
            #pragma unroll
            for (int d = 1; d < 16; d <<= 1) s += __shfl_xor(s, d);
            float rs = __frcp_rn(s);
            u16* pp = &Sb[rr * 232];
            #pragma unroll
            for (int c = 0; c < 14; c++)
                pp[l16 + c * 16] = f2bf(vals[c] * rs);
        }
    }
    __syncthreads();

    f32x4 oacc[4];
    #pragma unroll
    for (int nt = 0; nt < 4; nt++) { f32x4 z = {0.f,0.f,0.f,0.f}; oacc[nt] = z; }
    #pragma unroll
    for (int ks = 0; ks < 7; ks++) {
        bf16x8 pa = *(const bf16x8*)&Sb[(w * 16 + m) * 232 + ks * 32 + quad * 8];
        #pragma unroll
        for (int nt = 0; nt < 4; nt++) {
            int ad = (nt * 16 + m) * 234 + ks * 32 + quad * 8;
            union { u32 u[4]; bf16x8 v; } vb;
            vb.u[0] = *(const u32*)&Kb[ad];
            vb.u[1] = *(const u32*)&Kb[ad + 2];
            vb.u[2] = *(const u32*)&Kb[ad + 4];
            vb.u[3] = *(const u32*)&Kb[ad + 6];
            oacc[nt] = __builtin_amdgcn_mfma_f32_16x16x32_bf16(pa, vb.v, oacc[nt], 0, 0, 0);
        }
    }
    #pragma unroll
    for (int nt = 0; nt < 4; nt++) {
        #pragma unroll
        for (int reg = 0; reg < 4; reg++) {
            int rr = w * 16 + quad * 4 + reg;
            int tok = (ti + (rr >> 3)) * 32 + (tj + (rr & 7));
            ob[(size_t)(n * 1024 + tok) * 512 + h * 64 + nt * 16 + m] = f2bf(oacc[nt][reg]);
        }
    }
}

extern "C" void kernel_launch(void* const* d_in, const int* in_sizes, int n_in,
                              void* d_out, int out_size, void* d_ws, size_t ws_size,
                              hipStream_t stream)
{
    // Match inputs by unique element count (robust to ordering).
    const float *x = nullptr, *pos = nullptr, *cond = nullptr, *w_cond = nullptr,
                *w_qkv = nullptr, *scale = nullptr, *w_out = nullptr;
    for (int i = 0; i < n_in; i++) {
        switch (in_sizes[i]) {
            case 1048576: x      = (const float*)d_in[i]; break;  // 2*32*32*512
            case 2048:    pos    = (const float*)d_in[i]; break;  // 2*32*32*1
            case 1536:    cond   = (const float*)d_in[i]; break;  // 2*768
            case 393216:  w_cond = (const float*)d_in[i]; break;  // 512*768
            case 786432:  w_qkv  = (const float*)d_in[i]; break;  // 1536*512
            case 8:       scale  = (const float*)d_in[i]; break;  // 8
            case 262144:  w_out  = (const float*)d_in[i]; break;  // 512*512
            default: break;
        }
    }
    float* out = (float*)d_out;   // FLOAT32 output

    // ws: ns 4K | inv 8K | wqkvb 1.5M | woutb .5M | qp/kp/vp 2M each | ob 2M
    char* ws = (char*)d_ws;
    float* ns    = (float*)ws;                          // [2][512]
    float* inv   = (float*)(ws + 4096);                 // [2048]
    u16*   wqkvb = (u16*)(ws + 12288);                  // [1536][512]  bf16
    u16*   woutb = (u16*)(ws + 12288 + 1572864);        // [512][512]   bf16
    u16*   qp    = (u16*)(ws + 12288 + 2097152);        // [2][8][1024][64] bf16
    u16*   kp    = (u16*)(ws + 12288 + 4194304);        // same
    u16*   vp    = (u16*)(ws + 12288 + 6291456);        // same
    u16*   ob    = (u16*)(ws + 12288 + 8388608);        // [2048][512]  bf16

    setup_kernel<<<1792, 256, 0, stream>>>(cond, w_cond, x, w_qkv, w_out, ns, inv, wqkvb, woutb);
    gemm_qkv<<<dim3(32, 24), 256, 0, stream>>>(x, ns, inv, wqkvb, pos, scale, qp, kp, vp);
    attn_mfma<<<256, 256, 0, stream>>>(qp, kp, vp, ob);
    gemm_out<<<dim3(32, 8), 256, 0, stream>>>(ob, woutb, out, x, 512, 512);
}

// Round 14
// 111.590 us; speedup vs baseline: 1.0785x; 1.0531x over previous
//
#include <hip/hip_runtime.h>

typedef unsigned short u16;
typedef unsigned int u32;
typedef __bf16 bf16x8 __attribute__((ext_vector_type(8)));
typedef float f32x4 __attribute__((ext_vector_type(4)));

__device__ __forceinline__ float bf2f(u16 v) {
    union { u32 u; float f; } c; c.u = ((u32)v) << 16; return c.f;
}
__device__ __forceinline__ u16 f2bf(float f) {
    union { float f; u32 u; } c; c.f = f;
    u32 u = c.u + 0x7fffu + ((c.u >> 16) & 1u);   // RNE
    return (u16)(u >> 16);
}

// ---------------- K1: blocks 0..255 cond_scale | 256..1023 w_qkv->bf16 | 1024..1279 w_out->bf16
__global__ __launch_bounds__(256) void setup_kernel(
    const float* __restrict__ cond, const float* __restrict__ w_cond,
    const float* __restrict__ w_qkv, const float* __restrict__ w_out,
    float* __restrict__ ns, u16* __restrict__ wqkvb, u16* __restrict__ woutb)
{
    int b = blockIdx.x;
    if (b < 256) {
        int lane = threadIdx.x & 63;
        int wid = b * 4 + (threadIdx.x >> 6); // 0..1023
        int n = wid >> 9, c = wid & 511;
        const float* cp = cond + n * 768;
        const float* wp = w_cond + (size_t)c * 768;
        float s = 0.f;
        #pragma unroll
        for (int j = 0; j < 12; j++)
            s += cp[lane + j * 64] * wp[lane + j * 64];
        #pragma unroll
        for (int d = 1; d < 64; d <<= 1) s += __shfl_xor(s, d);
        if (lane == 0) ns[wid] = s + 1.f;
    } else {
        const float* src; u16* dst; size_t i4;
        if (b < 1024) { src = w_qkv; dst = wqkvb; i4 = (size_t)(b - 256)  * 1024 + threadIdx.x * 4; }
        else          { src = w_out; dst = woutb; i4 = (size_t)(b - 1024) * 1024 + threadIdx.x * 4; }
        float4 v = *(const float4*)(src + i4);
        ushort4 o; o.x = f2bf(v.x); o.y = f2bf(v.y); o.z = f2bf(v.z); o.w = f2bf(v.w);
        *(ushort4*)(dst + i4) = o;
    }
}

// ---------------- K2: fused per-row RMS + scale + bf16 convert. One wave per token row.
__global__ __launch_bounds__(256) void rmsxn_kernel(
    const float* __restrict__ x, const float* __restrict__ ns, u16* __restrict__ xn)
{
    int w = threadIdx.x >> 6, lane = threadIdx.x & 63;
    int p = blockIdx.x * 4 + w;   // 0..2047
    int n = p >> 10;
    const float* xp = x + (size_t)p * 512;
    const float* nsp = ns + n * 512;
    float4 v0 = *(const float4*)(xp + lane * 4);
    float4 v1 = *(const float4*)(xp + 256 + lane * 4);
    float ss = v0.x * v0.x + v0.y * v0.y + v0.z * v0.z + v0.w * v0.w
             + v1.x * v1.x + v1.y * v1.y + v1.z * v1.z + v1.w * v1.w;
    #pragma unroll
    for (int d = 1; d < 64; d <<= 1) ss += __shfl_xor(ss, d);
    float inv = rsqrtf(ss * (1.f / 512.f) + 1e-6f);
    float4 n0 = *(const float4*)(nsp + lane * 4);
    float4 n1 = *(const float4*)(nsp + 256 + lane * 4);
    ushort4 o0, o1;
    o0.x = f2bf(v0.x * n0.x * inv); o0.y = f2bf(v0.y * n0.y * inv);
    o0.z = f2bf(v0.z * n0.z * inv); o0.w = f2bf(v0.w * n0.w * inv);
    o1.x = f2bf(v1.x * n1.x * inv); o1.y = f2bf(v1.y * n1.y * inv);
    o1.z = f2bf(v1.z * n1.z * inv); o1.w = f2bf(v1.w * n1.w * inv);
    *(ushort4*)(xn + (size_t)p * 512 + lane * 4) = o0;
    *(ushort4*)(xn + (size_t)p * 512 + 256 + lane * 4) = o1;
}

// ---------------- K3: qkv GEMM, 64x64 tile, BK=64 double-staged (8 MFMA/barrier-pair),
// q/k head-norm + RoPE fused in epilogue. Writes head-major bf16 planes.
// Block (bx,by): rows bx*64 tokens, cols = one (qk,head) slice (by: 0..7 q / 8..15 k / 16..23 v).
// A-frag: m=lane&15, k=quad*8+j ; C/D: col=ci*16+m (within wn half), row=quad*4+reg [m89/m91]
// RoPE pair (d, d+16), d<16: ci=0/ci=1 of wn==0 wave -> register-local rotation.
__global__ __launch_bounds__(256) void gemm_qkv(
    const u16* __restrict__ A, const u16* __restrict__ B,
    const float* __restrict__ pos, const float* __restrict__ scale,
    u16* __restrict__ qp, u16* __restrict__ kp, u16* __restrict__ vp)
{
    __shared__ __align__(16) u16 As[2][64][40];
    __shared__ __align__(16) u16 Bs[2][64][40];
    int tid = threadIdx.x;
    int lane = tid & 63;
    int w = tid >> 6;
    int wm = w >> 1, wn = w & 1;
    int bm = blockIdx.x * 64, bn = blockIdx.y * 64;
    int qk = blockIdx.y >> 3, h = blockIdx.y & 7;
    int lrow = tid >> 2, lc8 = (tid & 3) * 8;

    f32x4 zero = {0.f, 0.f, 0.f, 0.f};
    f32x4 acc[2][2];
    acc[0][0] = zero; acc[0][1] = zero; acc[1][0] = zero; acc[1][1] = zero;

    const u16* Ap = A + (size_t)(bm + lrow) * 512 + lc8;
    const u16* Bp = B + (size_t)(bn + lrow) * 512 + lc8;
    int m = lane & 15, quad = lane >> 4, kq = quad * 8;

    for (int k0 = 0; k0 < 512; k0 += 64) {
        *(uint4*)&As[0][lrow][lc8] = *(const uint4*)(Ap + k0);
        *(uint4*)&As[1][lrow][lc8] = *(const uint4*)(Ap + k0 + 32);
        *(uint4*)&Bs[0][lrow][lc8] = *(const uint4*)(Bp + k0);
        *(uint4*)&Bs[1][lrow][lc8] = *(const uint4*)(Bp + k0 + 32);
        __syncthreads();
        #pragma unroll
        for (int kk = 0; kk < 2; kk++)
        #pragma unroll
        for (int ri = 0; ri < 2; ri++) {
            bf16x8 af = *(const bf16x8*)&As[kk][wm * 32 + ri * 16 + m][kq];
            #pragma unroll
            for (int ci = 0; ci < 2; ci++) {
                bf16x8 bfr = *(const bf16x8*)&Bs[kk][wn * 32 + ci * 16 + m][kq];
                acc[ri][ci] = __builtin_amdgcn_mfma_f32_16x16x32_bf16(af, bfr, acc[ri][ci], 0, 0, 0);
            }
        }
        __syncthreads();
    }

    // ---- epilogue: head-norm (sum over 64 cols via cross-wave LDS) + RoPE for q/k
    float invn[2][4];
    if (qk < 2) {
        float* red = (float*)As;   // [64][2] partials, reuse LDS
        #pragma unroll
        for (int ri = 0; ri < 2; ri++)
        #pragma unroll
        for (int reg = 0; reg < 4; reg++) {
            float pa = acc[ri][0][reg] * acc[ri][0][reg]
                     + acc[ri][1][reg] * acc[ri][1][reg];
            #pragma unroll
            for (int d = 1; d < 16; d <<= 1) pa += __shfl_xor(pa, d);
            if (m == 0) red[(wm * 32 + ri * 16 + quad * 4 + reg) * 2 + wn] = pa;
        }
        __syncthreads();
        float sq = sqrtf(scale[h]);
        #pragma unroll
        for (int ri = 0; ri < 2; ri++)
        #pragma unroll
        for (int reg = 0; reg < 4; reg++) {
            int rl = wm * 32 + ri * 16 + quad * 4 + reg;
            invn[ri][reg] = sq * rsqrtf(red[rl * 2] + red[rl * 2 + 1] + 1e-6f);
        }
    }
    u16* plane = (qk == 0) ? qp : (qk == 1) ? kp : vp;
    // freqs[h][t] = pi * 10^((t*8+h)/128), t = m
    float fr = 3.14159265358979323846f * expf((float)(m * 8 + h) * (2.302585092994046f / 128.f));
    #pragma unroll
    for (int ri = 0; ri < 2; ri++)
    #pragma unroll
    for (int reg = 0; reg < 4; reg++) {
        int rl = wm * 32 + ri * 16 + quad * 4 + reg;
        int p = bm + rl;
        size_t basep = ((size_t)((p >> 10) * 8 + h) * 1024 + (p & 1023)) * 64;
        float v0 = acc[ri][0][reg], v1 = acc[ri][1][reg];
        if (qk < 2) {
            float ivn = invn[ri][reg];
            v0 *= ivn; v1 *= ivn;
            if (wn == 0) {   // dims 0..31: rotate (d, d+16)
                float th = pos[p] * fr;
                float cs = cosf(th), sn = sinf(th);
                float o0 = v0 * cs - v1 * sn;
                float o1 = v1 * cs + v0 * sn;
                v0 = o0; v1 = o1;
            }
        }
        plane[basep + wn * 32 + m]      = f2bf(v0);
        plane[basep + wn * 32 + 16 + m] = f2bf(v1);
    }
}

// ---------------- K5: MFMA GEMM (out proj), BK=64 double-staged: C fp32 = A @ B^T + skip
__global__ __launch_bounds__(256) void gemm_out(
    const u16* __restrict__ A, const u16* __restrict__ B,
    float* __restrict__ C, const float* __restrict__ skip, int N, int K)
{
    __shared__ __align__(16) u16 As[2][64][40];
    __shared__ __align__(16) u16 Bs[2][64][40];
    int tid = threadIdx.x;
    int lane = tid & 63;
    int w = tid >> 6;
    int wm = w >> 1, wn = w & 1;
    int bm = blockIdx.x * 64, bn = blockIdx.y * 64;
    int lrow = tid >> 2, lc8 = (tid & 3) * 8;

    f32x4 zero = {0.f, 0.f, 0.f, 0.f};
    f32x4 acc[2][2];
    acc[0][0] = zero; acc[0][1] = zero; acc[1][0] = zero; acc[1][1] = zero;

    const u16* Ap = A + (size_t)(bm + lrow) * K + lc8;
    const u16* Bp = B + (size_t)(bn + lrow) * K + lc8;
    int r = lane & 15, kq = (lane >> 4) * 8;

    for (int k0 = 0; k0 < K; k0 += 64) {
        *(uint4*)&As[0][lrow][lc8] = *(const uint4*)(Ap + k0);
        *(uint4*)&As[1][lrow][lc8] = *(const uint4*)(Ap + k0 + 32);
        *(uint4*)&Bs[0][lrow][lc8] = *(const uint4*)(Bp + k0);
        *(uint4*)&Bs[1][lrow][lc8] = *(const uint4*)(Bp + k0 + 32);
        __syncthreads();
        #pragma unroll
        for (int kk = 0; kk < 2; kk++)
        #pragma unroll
        for (int ri = 0; ri < 2; ri++) {
            bf16x8 af = *(const bf16x8*)&As[kk][wm * 32 + ri * 16 + r][kq];
            #pragma unroll
            for (int ci = 0; ci < 2; ci++) {
                bf16x8 bfr = *(const bf16x8*)&Bs[kk][wn * 32 + ci * 16 + r][kq];
                acc[ri][ci] = __builtin_amdgcn_mfma_f32_16x16x32_bf16(af, bfr, acc[ri][ci], 0, 0, 0);
            }
        }
        __syncthreads();
    }

    #pragma unroll
    for (int ri = 0; ri < 2; ri++)
    #pragma unroll
    for (int ci = 0; ci < 2; ci++) {
        int col = bn + wn * 32 + ci * 16 + (lane & 15);
        int row0 = bm + wm * 32 + ri * 16 + (lane >> 4) * 4;
        #pragma unroll
        for (int reg = 0; reg < 4; reg++) {
            size_t idx = (size_t)(row0 + reg) * N + col;
            C[idx] = acc[ri][ci][reg] + skip[idx];
        }
    }
}

// ---------------- K4: MFMA neighborhood attention.
// One block per (n, h, 8x8 query tile). Union of neighborhoods = 14x14 = 196 keys.
__global__ __launch_bounds__(256) void attn_mfma(
    const u16* __restrict__ qp, const u16* __restrict__ kp, const u16* __restrict__ vp,
    u16* __restrict__ ob)
{
    __shared__ __align__(16) u16 Kb[208 * 72];   // K:[nb][64] stride 72; reused as Vt:[64][224] stride 234
    __shared__ __align__(16) u16 Sb[64 * 232];   // S fp16 then P bf16, row stride 232

    int tid = threadIdx.x, lane = tid & 63, w = tid >> 6;
    int bx = blockIdx.x;
    int n = bx >> 7, h = (bx >> 4) & 7, t = bx & 15;
    int ti = (t >> 2) * 8, tj = (t & 3) * 8;
    int r0 = min(max(ti - 3, 0), 18), c0 = min(max(tj - 3, 0), 18);
    const u16* qpl = qp + ((size_t)(n * 8 + h) << 16);
    const u16* kpl = kp + ((size_t)(n * 8 + h) << 16);
    const u16* vpl = vp + ((size_t)(n * 8 + h) << 16);

    for (int g = tid; g < 1568; g += 256) {
        int nb = g >> 3, k8 = (g & 7) << 3;
        int ar = nb / 14, ac = nb - ar * 14;
        *(uint4*)&Kb[nb * 72 + k8] =
            *(const uint4*)&kpl[(size_t)((r0 + ar) * 32 + c0 + ac) * 64 + k8];
    }
    __syncthreads();

    int m = lane & 15, quad = lane >> 4;
    {
        int r = w * 16 + m;
        int tok = (ti + (r >> 3)) * 32 + (tj + (r & 7));
        bf16x8 qf0 = *(const bf16x8*)&qpl[(size_t)tok * 64 + quad * 8];
        bf16x8 qf1 = *(const bf16x8*)&qpl[(size_t)tok * 64 + 32 + quad * 8];
        _Float16* sp = (_Float16*)Sb;
        #pragma unroll
        for (int nt = 0; nt < 13; nt++) {
            f32x4 acc = {0.f, 0.f, 0.f, 0.f};
            bf16x8 b0 = *(const bf16x8*)&Kb[(nt * 16 + m) * 72 + quad * 8];
            bf16x8 b1 = *(const bf16x8*)&Kb[(nt * 16 + m) * 72 + 32 + quad * 8];
            acc = __builtin_amdgcn_mfma_f32_16x16x32_bf16(qf0, b0, acc, 0, 0, 0);
            acc = __builtin_amdgcn_mfma_f32_16x16x32_bf16(qf1, b1, acc, 0, 0, 0);
            #pragma unroll
            for (int reg = 0; reg < 4; reg++)
                sp[(w * 16 + quad * 4 + reg) * 232 + nt * 16 + m] = (_Float16)acc[reg];
        }
    }
    __syncthreads();

    for (int g = tid; g < 1568; g += 256) {
        int nb = g >> 3, k8 = (g & 7) << 3;
        int ar = nb / 14, ac = nb - ar * 14;
        uint4 v4 = *(const uint4*)&vpl[(size_t)((r0 + ar) * 32 + c0 + ac) * 64 + k8];
        u32 uu[4] = {v4.x, v4.y, v4.z, v4.w};
        #pragma unroll
        for (int e = 0; e < 4; e++) {
            Kb[(k8 + 2 * e) * 234 + nb]     = (u16)(uu[e] & 0xffff);
            Kb[(k8 + 2 * e + 1) * 234 + nb] = (u16)(uu[e] >> 16);
        }
    }
    for (int g = tid; g < 1792; g += 256) {
        int d = g / 28, nb = 196 + (g - d * 28);
        Kb[d * 234 + nb] = 0;
    }

    {
        int l16 = lane & 15, g4 = lane >> 4;
        #pragma unroll
        for (int it = 0; it < 4; it++) {
            int rr = w * 16 + it * 4 + g4;
            int i2 = ti + (rr >> 3), j2 = tj + (rr & 7);
            int alo = min(max(i2 - 3, 0), 25) - r0;
            int blo = min(max(j2 - 3, 0), 25) - c0;
            const _Float16* sp = (const _Float16*)&Sb[rr * 232];
            float vals[14];
            float mx = -1e30f;
            #pragma unroll
            for (int c = 0; c < 14; c++) {
                int col = l16 + c * 16;
                float v = -1e30f;
                if (col < 196) {
                    int ar = col / 14, ac = col - ar * 14;
                    if (ar >= alo && ar < alo + 7 && ac >= blo && ac < blo + 7)
                        v = (float)sp[col];
                }
                vals[c] = v; mx = fmaxf(mx, v);
            }
            #pragma unroll
            for (int d = 1; d < 16; d <<= 1) mx = fmaxf(mx, __shfl_xor(mx, d));
            float s = 0.f;
            #pragma unroll
            for (int c = 0; c < 14; c++) {
                float e = (vals[c] > -1e29f) ? expf(vals[c] - mx) : 0.f;
                vals[c] = e; s += e;
            }
            #pragma unroll
            for (int d = 1; d < 16; d <<= 1) s += __shfl_xor(s, d);
            float rs = __frcp_rn(s);
            u16* pp = &Sb[rr * 232];
            #pragma unroll
            for (int c = 0; c < 14; c++)
                pp[l16 + c * 16] = f2bf(vals[c] * rs);
        }
    }
    __syncthreads();

    f32x4 oacc[4];
    #pragma unroll
    for (int nt = 0; nt < 4; nt++) { f32x4 z = {0.f,0.f,0.f,0.f}; oacc[nt] = z; }
    #pragma unroll
    for (int ks = 0; ks < 7; ks++) {
        bf16x8 pa = *(const bf16x8*)&Sb[(w * 16 + m) * 232 + ks * 32 + quad * 8];
        #pragma unroll
        for (int nt = 0; nt < 4; nt++) {
            int ad = (nt * 16 + m) * 234 + ks * 32 + quad * 8;
            union { u32 u[4]; bf16x8 v; } vb;
            vb.u[0] = *(const u32*)&Kb[ad];
            vb.u[1] = *(const u32*)&Kb[ad + 2];
            vb.u[2] = *(const u32*)&Kb[ad + 4];
            vb.u[3] = *(const u32*)&Kb[ad + 6];
            oacc[nt] = __builtin_amdgcn_mfma_f32_16x16x32_bf16(pa, vb.v, oacc[nt], 0, 0, 0);
        }
    }
    #pragma unroll
    for (int nt = 0; nt < 4; nt++) {
        #pragma unroll
        for (int reg = 0; reg < 4; reg++) {
            int rr = w * 16 + quad * 4 + reg;
            int tok = (ti + (rr >> 3)) * 32 + (tj + (rr & 7));
            ob[(size_t)(n * 1024 + tok) * 512 + h * 64 + nt * 16 + m] = f2bf(oacc[nt][reg]);
        }
    }
}

extern "C" void kernel_launch(void* const* d_in, const int* in_sizes, int n_in,
                              void* d_out, int out_size, void* d_ws, size_t ws_size,
                              hipStream_t stream)
{
    // Match inputs by unique element count (robust to ordering).
    const float *x = nullptr, *pos = nullptr, *cond = nullptr, *w_cond = nullptr,
                *w_qkv = nullptr, *scale = nullptr, *w_out = nullptr;
    for (int i = 0; i < n_in; i++) {
        switch (in_sizes[i]) {
            case 1048576: x      = (const float*)d_in[i]; break;  // 2*32*32*512
            case 2048:    pos    = (const float*)d_in[i]; break;  // 2*32*32*1
            case 1536:    cond   = (const float*)d_in[i]; break;  // 2*768
            case 393216:  w_cond = (const float*)d_in[i]; break;  // 512*768
            case 786432:  w_qkv  = (const float*)d_in[i]; break;  // 1536*512
            case 8:       scale  = (const float*)d_in[i]; break;  // 8
            case 262144:  w_out  = (const float*)d_in[i]; break;  // 512*512
            default: break;
        }
    }
    float* out = (float*)d_out;   // FLOAT32 output

    // ws: ns 4K | wqkvb 1.5M | woutb .5M | xn 2M | qp/kp/vp 2M each | ob 2M
    char* ws = (char*)d_ws;
    float* ns    = (float*)ws;                          // [2][512]
    u16*   wqkvb = (u16*)(ws + 12288);                  // [1536][512]  bf16
    u16*   woutb = (u16*)(ws + 12288 + 1572864);        // [512][512]   bf16
    u16*   xn    = (u16*)(ws + 12288 + 2097152);        // [2048][512]  bf16
    u16*   qp    = (u16*)(ws + 12288 + 4194304);        // [2][8][1024][64] bf16
    u16*   kp    = (u16*)(ws + 12288 + 6291456);        // same
    u16*   vp    = (u16*)(ws + 12288 + 8388608);        // same
    u16*   ob    = (u16*)(ws + 12288 + 10485760);       // [2048][512]  bf16

    setup_kernel<<<1280, 256, 0, stream>>>(cond, w_cond, w_qkv, w_out, ns, wqkvb, woutb);
    rmsxn_kernel<<<512, 256, 0, stream>>>(x, ns, xn);
    gemm_qkv<<<dim3(32, 24), 256, 0, stream>>>(xn, wqkvb, pos, scale, qp, kp, vp);
    attn_mfma<<<256, 256, 0, stream>>>(qp, kp, vp, ob);
    gemm_out<<<dim3(32, 8), 256, 0, stream>>>(ob, woutb, out, x, 512, 512);
}

// Round 15
// 110.057 us; speedup vs baseline: 1.0935x; 1.0139x over previous
//
#include <hip/hip_runtime.h>

typedef unsigned short u16;
typedef unsigned int u32;
typedef __bf16 bf16x8 __attribute__((ext_vector_type(8)));
typedef float f32x4 __attribute__((ext_vector_type(4)));

__device__ __forceinline__ float bf2f(u16 v) {
    union { u32 u; float f; } c; c.u = ((u32)v) << 16; return c.f;
}
__device__ __forceinline__ u16 f2bf(float f) {
    union { float f; u32 u; } c; c.f = f;
    u32 u = c.u + 0x7fffu + ((c.u >> 16) & 1u);   // RNE
    return (u16)(u >> 16);
}

// ---------------- K1: blocks 0..255 cond_scale | 256..1023 w_qkv->bf16 | 1024..1279 w_out->bf16
__global__ __launch_bounds__(256) void setup_kernel(
    const float* __restrict__ cond, const float* __restrict__ w_cond,
    const float* __restrict__ w_qkv, const float* __restrict__ w_out,
    float* __restrict__ ns, u16* __restrict__ wqkvb, u16* __restrict__ woutb)
{
    int b = blockIdx.x;
    if (b < 256) {
        int lane = threadIdx.x & 63;
        int wid = b * 4 + (threadIdx.x >> 6); // 0..1023
        int n = wid >> 9, c = wid & 511;
        const float* cp = cond + n * 768;
        const float* wp = w_cond + (size_t)c * 768;
        float s = 0.f;
        #pragma unroll
        for (int j = 0; j < 12; j++)
            s += cp[lane + j * 64] * wp[lane + j * 64];
        #pragma unroll
        for (int d = 1; d < 64; d <<= 1) s += __shfl_xor(s, d);
        if (lane == 0) ns[wid] = s + 1.f;
    } else {
        const float* src; u16* dst; size_t i4;
        if (b < 1024) { src = w_qkv; dst = wqkvb; i4 = (size_t)(b - 256)  * 1024 + threadIdx.x * 4; }
        else          { src = w_out; dst = woutb; i4 = (size_t)(b - 1024) * 1024 + threadIdx.x * 4; }
        float4 v = *(const float4*)(src + i4);
        ushort4 o; o.x = f2bf(v.x); o.y = f2bf(v.y); o.z = f2bf(v.z); o.w = f2bf(v.w);
        *(ushort4*)(dst + i4) = o;
    }
}

// ---------------- K2: fused per-row RMS + scale + bf16 convert. One wave per token row.
__global__ __launch_bounds__(256) void rmsxn_kernel(
    const float* __restrict__ x, const float* __restrict__ ns, u16* __restrict__ xn)
{
    int w = threadIdx.x >> 6, lane = threadIdx.x & 63;
    int p = blockIdx.x * 4 + w;   // 0..2047
    int n = p >> 10;
    const float* xp = x + (size_t)p * 512;
    const float* nsp = ns + n * 512;
    float4 v0 = *(const float4*)(xp + lane * 4);
    float4 v1 = *(const float4*)(xp + 256 + lane * 4);
    float ss = v0.x * v0.x + v0.y * v0.y + v0.z * v0.z + v0.w * v0.w
             + v1.x * v1.x + v1.y * v1.y + v1.z * v1.z + v1.w * v1.w;
    #pragma unroll
    for (int d = 1; d < 64; d <<= 1) ss += __shfl_xor(ss, d);
    float inv = rsqrtf(ss * (1.f / 512.f) + 1e-6f);
    float4 n0 = *(const float4*)(nsp + lane * 4);
    float4 n1 = *(const float4*)(nsp + 256 + lane * 4);
    ushort4 o0, o1;
    o0.x = f2bf(v0.x * n0.x * inv); o0.y = f2bf(v0.y * n0.y * inv);
    o0.z = f2bf(v0.z * n0.z * inv); o0.w = f2bf(v0.w * n0.w * inv);
    o1.x = f2bf(v1.x * n1.x * inv); o1.y = f2bf(v1.y * n1.y * inv);
    o1.z = f2bf(v1.z * n1.z * inv); o1.w = f2bf(v1.w * n1.w * inv);
    *(ushort4*)(xn + (size_t)p * 512 + lane * 4) = o0;
    *(ushort4*)(xn + (size_t)p * 512 + 256 + lane * 4) = o1;
}

// ---------------- K3: qkv GEMM, 64x64 tile, BK=128 quad-staged (16 MFMA/barrier-pair),
// q/k head-norm + RoPE fused in epilogue. Writes head-major bf16 planes.
// Block (bx,by): rows bx*64 tokens, cols = one (qk,head) slice (by: 0..7 q / 8..15 k / 16..23 v).
// A-frag: m=lane&15, k=quad*8+j ; C/D: col=ci*16+m (within wn half), row=quad*4+reg [m89/m91]
// RoPE pair (d, d+16), d<16: ci=0/ci=1 of wn==0 wave -> register-local rotation.
__global__ __launch_bounds__(256) void gemm_qkv(
    const u16* __restrict__ A, const u16* __restrict__ B,
    const float* __restrict__ pos, const float* __restrict__ scale,
    u16* __restrict__ qp, u16* __restrict__ kp, u16* __restrict__ vp)
{
    __shared__ __align__(16) u16 As[4][64][40];
    __shared__ __align__(16) u16 Bs[4][64][40];
    int tid = threadIdx.x;
    int lane = tid & 63;
    int w = tid >> 6;
    int wm = w >> 1, wn = w & 1;
    int bm = blockIdx.x * 64, bn = blockIdx.y * 64;
    int qk = blockIdx.y >> 3, h = blockIdx.y & 7;
    int lrow = tid >> 2, lc8 = (tid & 3) * 8;

    f32x4 zero = {0.f, 0.f, 0.f, 0.f};
    f32x4 acc[2][2];
    acc[0][0] = zero; acc[0][1] = zero; acc[1][0] = zero; acc[1][1] = zero;

    const u16* Ap = A + (size_t)(bm + lrow) * 512 + lc8;
    const u16* Bp = B + (size_t)(bn + lrow) * 512 + lc8;
    int m = lane & 15, quad = lane >> 4, kq = quad * 8;

    for (int k0 = 0; k0 < 512; k0 += 128) {
        #pragma unroll
        for (int s = 0; s < 4; s++) {
            *(uint4*)&As[s][lrow][lc8] = *(const uint4*)(Ap + k0 + s * 32);
            *(uint4*)&Bs[s][lrow][lc8] = *(const uint4*)(Bp + k0 + s * 32);
        }
        __syncthreads();
        #pragma unroll
        for (int kk = 0; kk < 4; kk++)
        #pragma unroll
        for (int ri = 0; ri < 2; ri++) {
            bf16x8 af = *(const bf16x8*)&As[kk][wm * 32 + ri * 16 + m][kq];
            #pragma unroll
            for (int ci = 0; ci < 2; ci++) {
                bf16x8 bfr = *(const bf16x8*)&Bs[kk][wn * 32 + ci * 16 + m][kq];
                acc[ri][ci] = __builtin_amdgcn_mfma_f32_16x16x32_bf16(af, bfr, acc[ri][ci], 0, 0, 0);
            }
        }
        __syncthreads();
    }

    // ---- epilogue: head-norm (sum over 64 cols via cross-wave LDS) + RoPE for q/k
    float invn[2][4];
    if (qk < 2) {
        float* red = (float*)As;   // [64][2] partials, reuse LDS
        #pragma unroll
        for (int ri = 0; ri < 2; ri++)
        #pragma unroll
        for (int reg = 0; reg < 4; reg++) {
            float pa = acc[ri][0][reg] * acc[ri][0][reg]
                     + acc[ri][1][reg] * acc[ri][1][reg];
            #pragma unroll
            for (int d = 1; d < 16; d <<= 1) pa += __shfl_xor(pa, d);
            if (m == 0) red[(wm * 32 + ri * 16 + quad * 4 + reg) * 2 + wn] = pa;
        }
        __syncthreads();
        float sq = sqrtf(scale[h]);
        #pragma unroll
        for (int ri = 0; ri < 2; ri++)
        #pragma unroll
        for (int reg = 0; reg < 4; reg++) {
            int rl = wm * 32 + ri * 16 + quad * 4 + reg;
            invn[ri][reg] = sq * rsqrtf(red[rl * 2] + red[rl * 2 + 1] + 1e-6f);
        }
    }
    u16* plane = (qk == 0) ? qp : (qk == 1) ? kp : vp;
    // freqs[h][t] = pi * 10^((t*8+h)/128), t = m
    float fr = 3.14159265358979323846f * expf((float)(m * 8 + h) * (2.302585092994046f / 128.f));
    #pragma unroll
    for (int ri = 0; ri < 2; ri++)
    #pragma unroll
    for (int reg = 0; reg < 4; reg++) {
        int rl = wm * 32 + ri * 16 + quad * 4 + reg;
        int p = bm + rl;
        size_t basep = ((size_t)((p >> 10) * 8 + h) * 1024 + (p & 1023)) * 64;
        float v0 = acc[ri][0][reg], v1 = acc[ri][1][reg];
        if (qk < 2) {
            float ivn = invn[ri][reg];
            v0 *= ivn; v1 *= ivn;
            if (wn == 0) {   // dims 0..31: rotate (d, d+16)
                float th = pos[p] * fr;
                float cs = cosf(th), sn = sinf(th);
                float o0 = v0 * cs - v1 * sn;
                float o1 = v1 * cs + v0 * sn;
                v0 = o0; v1 = o1;
            }
        }
        plane[basep + wn * 32 + m]      = f2bf(v0);
        plane[basep + wn * 32 + 16 + m] = f2bf(v1);
    }
}

// ---------------- K5: MFMA GEMM (out proj), BK=128 quad-staged: C fp32 = A @ B^T + skip
__global__ __launch_bounds__(256) void gemm_out(
    const u16* __restrict__ A, const u16* __restrict__ B,
    float* __restrict__ C, const float* __restrict__ skip, int N, int K)
{
    __shared__ __align__(16) u16 As[4][64][40];
    __shared__ __align__(16) u16 Bs[4][64][40];
    int tid = threadIdx.x;
    int lane = tid & 63;
    int w = tid >> 6;
    int wm = w >> 1, wn = w & 1;
    int bm = blockIdx.x * 64, bn = blockIdx.y * 64;
    int lrow = tid >> 2, lc8 = (tid & 3) * 8;

    f32x4 zero = {0.f, 0.f, 0.f, 0.f};
    f32x4 acc[2][2];
    acc[0][0] = zero; acc[0][1] = zero; acc[1][0] = zero; acc[1][1] = zero;

    const u16* Ap = A + (size_t)(bm + lrow) * K + lc8;
    const u16* Bp = B + (size_t)(bn + lrow) * K + lc8;
    int r = lane & 15, kq = (lane >> 4) * 8;

    for (int k0 = 0; k0 < K; k0 += 128) {
        #pragma unroll
        for (int s = 0; s < 4; s++) {
            *(uint4*)&As[s][lrow][lc8] = *(const uint4*)(Ap + k0 + s * 32);
            *(uint4*)&Bs[s][lrow][lc8] = *(const uint4*)(Bp + k0 + s * 32);
        }
        __syncthreads();
        #pragma unroll
        for (int kk = 0; kk < 4; kk++)
        #pragma unroll
        for (int ri = 0; ri < 2; ri++) {
            bf16x8 af = *(const bf16x8*)&As[kk][wm * 32 + ri * 16 + r][kq];
            #pragma unroll
            for (int ci = 0; ci < 2; ci++) {
                bf16x8 bfr = *(const bf16x8*)&Bs[kk][wn * 32 + ci * 16 + r][kq];
                acc[ri][ci] = __builtin_amdgcn_mfma_f32_16x16x32_bf16(af, bfr, acc[ri][ci], 0, 0, 0);
            }
        }
        __syncthreads();
    }

    #pragma unroll
    for (int ri = 0; ri < 2; ri++)
    #pragma unroll
    for (int ci = 0; ci < 2; ci++) {
        int col = bn + wn * 32 + ci * 16 + (lane & 15);
        int row0 = bm + wm * 32 + ri * 16 + (lane >> 4) * 4;
        #pragma unroll
        for (int reg = 0; reg < 4; reg++) {
            size_t idx = (size_t)(row0 + reg) * N + col;
            C[idx] = acc[ri][ci][reg] + skip[idx];
        }
    }
}

// ---------------- K4: MFMA neighborhood attention.
// One block per (n, h, 8x8 query tile). Union of neighborhoods = 14x14 = 196 keys.
__global__ __launch_bounds__(256) void attn_mfma(
    const u16* __restrict__ qp, const u16* __restrict__ kp, const u16* __restrict__ vp,
    u16* __restrict__ ob)
{
    __shared__ __align__(16) u16 Kb[208 * 72];   // K:[nb][64] stride 72; reused as Vt:[64][224] stride 234
    __shared__ __align__(16) u16 Sb[64 * 232];   // S fp16 then P bf16, row stride 232

    int tid = threadIdx.x, lane = tid & 63, w = tid >> 6;
    int bx = blockIdx.x;
    int n = bx >> 7, h = (bx >> 4) & 7, t = bx & 15;
    int ti = (t >> 2) * 8, tj = (t & 3) * 8;
    int r0 = min(max(ti - 3, 0), 18), c0 = min(max(tj - 3, 0), 18);
    const u16* qpl = qp + ((size_t)(n * 8 + h) << 16);
    const u16* kpl = kp + ((size_t)(n * 8 + h) << 16);
    const u16* vpl = vp + ((size_t)(n * 8 + h) << 16);

    for (int g = tid; g < 1568; g += 256) {
        int nb = g >> 3, k8 = (g & 7) << 3;
        int ar = nb / 14, ac = nb - ar * 14;
        *(uint4*)&Kb[nb * 72 + k8] =
            *(const uint4*)&kpl[(size_t)((r0 + ar) * 32 + c0 + ac) * 64 + k8];
    }
    __syncthreads();

    int m = lane & 15, quad = lane >> 4;
    {
        int r = w * 16 + m;
        int tok = (ti + (r >> 3)) * 32 + (tj + (r & 7));
        bf16x8 qf0 = *(const bf16x8*)&qpl[(size_t)tok * 64 + quad * 8];
        bf16x8 qf1 = *(const bf16x8*)&qpl[(size_t)tok * 64 + 32 + quad * 8];
        _Float16* sp = (_Float16*)Sb;
        #pragma unroll
        for (int nt = 0; nt < 13; nt++) {
            f32x4 acc = {0.f, 0.f, 0.f, 0.f};
            bf16x8 b0 = *(const bf16x8*)&Kb[(nt * 16 + m) * 72 + quad * 8];
            bf16x8 b1 = *(const bf16x8*)&Kb[(nt * 16 + m) * 72 + 32 + quad * 8];
            acc = __builtin_amdgcn_mfma_f32_16x16x32_bf16(qf0, b0, acc, 0, 0, 0);
            acc = __builtin_amdgcn_mfma_f32_16x16x32_bf16(qf1, b1, acc, 0, 0, 0);
            #pragma unroll
            for (int reg = 0; reg < 4; reg++)
                sp[(w * 16 + quad * 4 + reg) * 232 + nt * 16 + m] = (_Float16)acc[reg];
        }
    }
    __syncthreads();

    for (int g = tid; g < 1568; g += 256) {
        int nb = g >> 3, k8 = (g & 7) << 3;
        int ar = nb / 14, ac = nb - ar * 14;
        uint4 v4 = *(const uint4*)&vpl[(size_t)((r0 + ar) * 32 + c0 + ac) * 64 + k8];
        u32 uu[4] = {v4.x, v4.y, v4.z, v4.w};
        #pragma unroll
        for (int e = 0; e < 4; e++) {
            Kb[(k8 + 2 * e) * 234 + nb]     = (u16)(uu[e] & 0xffff);
            Kb[(k8 + 2 * e + 1) * 234 + nb] = (u16)(uu[e] >> 16);
        }
    }
    for (int g = tid; g < 1792; g += 256) {
        int d = g / 28, nb = 196 + (g - d * 28);
        Kb[d * 234 + nb] = 0;
    }

    {
        int l16 = lane & 15, g4 = lane >> 4;
        #pragma unroll
        for (int it = 0; it < 4; it++) {
            int rr = w * 16 + it * 4 + g4;
            int i2 = ti + (rr >> 3), j2 = tj + (rr & 7);
            int alo = min(max(i2 - 3, 0), 25) - r0;
            int blo = min(max(j2 - 3, 0), 25) - c0;
            const _Float16* sp = (const _Float16*)&Sb[rr * 232];
            float vals[14];
            float mx = -1e30f;
            #pragma unroll
            for (int c = 0; c < 14; c++) {
                int col = l16 + c * 16;
                float v = -1e30f;
                if (col < 196) {
                    int ar = col / 14, ac = col - ar * 14;
                    if (ar >= alo && ar < alo + 7 && ac >= blo && ac < blo + 7)
                        v = (float)sp[col];
                }
                vals[c] = v; mx = fmaxf(mx, v);
            }
            #pragma unroll
            for (int d = 1; d < 16; d <<= 1) mx = fmaxf(mx, __shfl_xor(mx, d));
            float s = 0.f;
            #pragma unroll
            for (int c = 0; c < 14; c++) {
                float e = (vals[c] > -1e29f) ? expf(vals[c] - mx) : 0.f;
                vals[c] = e; s += e;
            }
            #pragma unroll
            for (int d = 1; d < 16; d <<= 1) s += __shfl_xor(s, d);
            float rs = __frcp_rn(s);
            u16* pp = &Sb[rr * 232];
            #pragma unroll
            for (int c = 0; c < 14; c++)
                pp[l16 + c * 16] = f2bf(vals[c] * rs);
        }
    }
    __syncthreads();

    f32x4 oacc[4];
    #pragma unroll
    for (int nt = 0; nt < 4; nt++) { f32x4 z = {0.f,0.f,0.f,0.f}; oacc[nt] = z; }
    #pragma unroll
    for (int ks = 0; ks < 7; ks++) {
        bf16x8 pa = *(const bf16x8*)&Sb[(w * 16 + m) * 232 + ks * 32 + quad * 8];
        #pragma unroll
        for (int nt = 0; nt < 4; nt++) {
            int ad = (nt * 16 + m) * 234 + ks * 32 + quad * 8;
            union { u32 u[4]; bf16x8 v; } vb;
            vb.u[0] = *(const u32*)&Kb[ad];
            vb.u[1] = *(const u32*)&Kb[ad + 2];
            vb.u[2] = *(const u32*)&Kb[ad + 4];
            vb.u[3] = *(const u32*)&Kb[ad + 6];
            oacc[nt] = __builtin_amdgcn_mfma_f32_16x16x32_bf16(pa, vb.v, oacc[nt], 0, 0, 0);
        }
    }
    #pragma unroll
    for (int nt = 0; nt < 4; nt++) {
        #pragma unroll
        for (int reg = 0; reg < 4; reg++) {
            int rr = w * 16 + quad * 4 + reg;
            int tok = (ti + (rr >> 3)) * 32 + (tj + (rr & 7));
            ob[(size_t)(n * 1024 + tok) * 512 + h * 64 + nt * 16 + m] = f2bf(oacc[nt][reg]);
        }
    }
}

extern "C" void kernel_launch(void* const* d_in, const int* in_sizes, int n_in,
                              void* d_out, int out_size, void* d_ws, size_t ws_size,
                              hipStream_t stream)
{
    // Match inputs by unique element count (robust to ordering).
    const float *x = nullptr, *pos = nullptr, *cond = nullptr, *w_cond = nullptr,
                *w_qkv = nullptr, *scale = nullptr, *w_out = nullptr;
    for (int i = 0; i < n_in; i++) {
        switch (in_sizes[i]) {
            case 1048576: x      = (const float*)d_in[i]; break;  // 2*32*32*512
            case 2048:    pos    = (const float*)d_in[i]; break;  // 2*32*32*1
            case 1536:    cond   = (const float*)d_in[i]; break;  // 2*768
            case 393216:  w_cond = (const float*)d_in[i]; break;  // 512*768
            case 786432:  w_qkv  = (const float*)d_in[i]; break;  // 1536*512
            case 8:       scale  = (const float*)d_in[i]; break;  // 8
            case 262144:  w_out  = (const float*)d_in[i]; break;  // 512*512
            default: break;
        }
    }
    float* out = (float*)d_out;   // FLOAT32 output

    // ws: ns 4K | wqkvb 1.5M | woutb .5M | xn 2M | qp/kp/vp 2M each | ob 2M
    char* ws = (char*)d_ws;
    float* ns    = (float*)ws;                          // [2][512]
    u16*   wqkvb = (u16*)(ws + 12288);                  // [1536][512]  bf16
    u16*   woutb = (u16*)(ws + 12288 + 1572864);        // [512][512]   bf16
    u16*   xn    = (u16*)(ws + 12288 + 2097152);        // [2048][512]  bf16
    u16*   qp    = (u16*)(ws + 12288 + 4194304);        // [2][8][1024][64] bf16
    u16*   kp    = (u16*)(ws + 12288 + 6291456);        // same
    u16*   vp    = (u16*)(ws + 12288 + 8388608);        // same
    u16*   ob    = (u16*)(ws + 12288 + 10485760);       // [2048][512]  bf16

    setup_kernel<<<1280, 256, 0, stream>>>(cond, w_cond, w_qkv, w_out, ns, wqkvb, woutb);
    rmsxn_kernel<<<512, 256, 0, stream>>>(x, ns, xn);
    gemm_qkv<<<dim3(32, 24), 256, 0, stream>>>(xn, wqkvb, pos, scale, qp, kp, vp);
    attn_mfma<<<256, 256, 0, stream>>>(qp, kp, vp, ob);
    gemm_out<<<dim3(32, 8), 256, 0, stream>>>(ob, woutb, out, x, 512, 512);
}

// Round 17
// 109.967 us; speedup vs baseline: 1.0944x; 1.0008x over previous
//
#include <hip/hip_runtime.h>

typedef unsigned short u16;
typedef unsigned int u32;
typedef __bf16 bf16x8 __attribute__((ext_vector_type(8)));
typedef float f32x4 __attribute__((ext_vector_type(4)));

__device__ __forceinline__ float bf2f(u16 v) {
    union { u32 u; float f; } c; c.u = ((u32)v) << 16; return c.f;
}
__device__ __forceinline__ u16 f2bf(float f) {
    union { float f; u32 u; } c; c.f = f;
    u32 u = c.u + 0x7fffu + ((c.u >> 16) & 1u);   // RNE
    return (u16)(u >> 16);
}

// ---------------- K1: cond_scale only -> ns[2][512]
__global__ __launch_bounds__(256) void cond_kernel(
    const float* __restrict__ cond, const float* __restrict__ w_cond, float* __restrict__ ns)
{
    int lane = threadIdx.x & 63;
    int wid = blockIdx.x * 4 + (threadIdx.x >> 6); // 0..1023
    int n = wid >> 9, c = wid & 511;
    const float* cp = cond + n * 768;
    const float* wp = w_cond + (size_t)c * 768;
    float s = 0.f;
    #pragma unroll
    for (int j = 0; j < 12; j++)
        s += cp[lane + j * 64] * wp[lane + j * 64];
    #pragma unroll
    for (int d = 1; d < 64; d <<= 1) s += __shfl_xor(s, d);
    if (lane == 0) ns[wid] = s + 1.f;
}

// ---------------- K2: blocks 0..511 rmsxn | 512..1279 w_qkv->bf16 | 1280..1535 w_out->bf16
__global__ __launch_bounds__(256) void prep_kernel(
    const float* __restrict__ x, const float* __restrict__ ns,
    const float* __restrict__ w_qkv, const float* __restrict__ w_out,
    u16* __restrict__ xn, u16* __restrict__ wqkvb, u16* __restrict__ woutb)
{
    int b = blockIdx.x;
    if (b < 512) {
        int w = threadIdx.x >> 6, lane = threadIdx.x & 63;
        int p = b * 4 + w;   // 0..2047
        int n = p >> 10;
        const float* xp = x + (size_t)p * 512;
        const float* nsp = ns + n * 512;
        float4 v0 = *(const float4*)(xp + lane * 4);
        float4 v1 = *(const float4*)(xp + 256 + lane * 4);
        float ss = v0.x * v0.x + v0.y * v0.y + v0.z * v0.z + v0.w * v0.w
                 + v1.x * v1.x + v1.y * v1.y + v1.z * v1.z + v1.w * v1.w;
        #pragma unroll
        for (int d = 1; d < 64; d <<= 1) ss += __shfl_xor(ss, d);
        float inv = rsqrtf(ss * (1.f / 512.f) + 1e-6f);
        float4 n0 = *(const float4*)(nsp + lane * 4);
        float4 n1 = *(const float4*)(nsp + 256 + lane * 4);
        ushort4 o0, o1;
        o0.x = f2bf(v0.x * n0.x * inv); o0.y = f2bf(v0.y * n0.y * inv);
        o0.z = f2bf(v0.z * n0.z * inv); o0.w = f2bf(v0.w * n0.w * inv);
        o1.x = f2bf(v1.x * n1.x * inv); o1.y = f2bf(v1.y * n1.y * inv);
        o1.z = f2bf(v1.z * n1.z * inv); o1.w = f2bf(v1.w * n1.w * inv);
        *(ushort4*)(xn + (size_t)p * 512 + lane * 4) = o0;
        *(ushort4*)(xn + (size_t)p * 512 + 256 + lane * 4) = o1;
    } else {
        const float* src; u16* dst; size_t i4;
        if (b < 1280) { src = w_qkv; dst = wqkvb; i4 = (size_t)(b - 512)  * 1024 + threadIdx.x * 4; }
        else          { src = w_out; dst = woutb; i4 = (size_t)(b - 1280) * 1024 + threadIdx.x * 4; }
        float4 v = *(const float4*)(src + i4);
        ushort4 o; o.x = f2bf(v.x); o.y = f2bf(v.y); o.z = f2bf(v.z); o.w = f2bf(v.w);
        *(ushort4*)(dst + i4) = o;
    }
}

// ---------------- K3: qkv GEMM, 64x64 tile, BK=128 quad-staged (16 MFMA/barrier-pair),
// q/k head-norm + RoPE fused in epilogue. Writes head-major bf16 planes.
// Block (bx,by): rows bx*64 tokens, cols = one (qk,head) slice (by: 0..7 q / 8..15 k / 16..23 v).
// A-frag: m=lane&15, k=quad*8+j ; C/D: col=ci*16+m (within wn half), row=quad*4+reg [m89/m91]
// RoPE pair (d, d+16), d<16: ci=0/ci=1 of wn==0 wave -> register-local rotation.
__global__ __launch_bounds__(256) void gemm_qkv(
    const u16* __restrict__ A, const u16* __restrict__ B,
    const float* __restrict__ pos, const float* __restrict__ scale,
    u16* __restrict__ qp, u16* __restrict__ kp, u16* __restrict__ vp)
{
    __shared__ __align__(16) u16 As[4][64][40];
    __shared__ __align__(16) u16 Bs[4][64][40];
    int tid = threadIdx.x;
    int lane = tid & 63;
    int w = tid >> 6;
    int wm = w >> 1, wn = w & 1;
    int bm = blockIdx.x * 64, bn = blockIdx.y * 64;
    int qk = blockIdx.y >> 3, h = blockIdx.y & 7;
    int lrow = tid >> 2, lc8 = (tid & 3) * 8;

    f32x4 zero = {0.f, 0.f, 0.f, 0.f};
    f32x4 acc[2][2];
    acc[0][0] = zero; acc[0][1] = zero; acc[1][0] = zero; acc[1][1] = zero;

    const u16* Ap = A + (size_t)(bm + lrow) * 512 + lc8;
    const u16* Bp = B + (size_t)(bn + lrow) * 512 + lc8;
    int m = lane & 15, quad = lane >> 4, kq = quad * 8;

    for (int k0 = 0; k0 < 512; k0 += 128) {
        #pragma unroll
        for (int s = 0; s < 4; s++) {
            *(uint4*)&As[s][lrow][lc8] = *(const uint4*)(Ap + k0 + s * 32);
            *(uint4*)&Bs[s][lrow][lc8] = *(const uint4*)(Bp + k0 + s * 32);
        }
        __syncthreads();
        #pragma unroll
        for (int kk = 0; kk < 4; kk++)
        #pragma unroll
        for (int ri = 0; ri < 2; ri++) {
            bf16x8 af = *(const bf16x8*)&As[kk][wm * 32 + ri * 16 + m][kq];
            #pragma unroll
            for (int ci = 0; ci < 2; ci++) {
                bf16x8 bfr = *(const bf16x8*)&Bs[kk][wn * 32 + ci * 16 + m][kq];
                acc[ri][ci] = __builtin_amdgcn_mfma_f32_16x16x32_bf16(af, bfr, acc[ri][ci], 0, 0, 0);
            }
        }
        __syncthreads();
    }

    // ---- epilogue: head-norm (sum over 64 cols via cross-wave LDS) + RoPE for q/k
    float invn[2][4];
    if (qk < 2) {
        float* red = (float*)As;   // [64][2] partials, reuse LDS
        #pragma unroll
        for (int ri = 0; ri < 2; ri++)
        #pragma unroll
        for (int reg = 0; reg < 4; reg++) {
            float pa = acc[ri][0][reg] * acc[ri][0][reg]
                     + acc[ri][1][reg] * acc[ri][1][reg];
            #pragma unroll
            for (int d = 1; d < 16; d <<= 1) pa += __shfl_xor(pa, d);
            if (m == 0) red[(wm * 32 + ri * 16 + quad * 4 + reg) * 2 + wn] = pa;
        }
        __syncthreads();
        float sq = sqrtf(scale[h]);
        #pragma unroll
        for (int ri = 0; ri < 2; ri++)
        #pragma unroll
        for (int reg = 0; reg < 4; reg++) {
            int rl = wm * 32 + ri * 16 + quad * 4 + reg;
            invn[ri][reg] = sq * rsqrtf(red[rl * 2] + red[rl * 2 + 1] + 1e-6f);
        }
    }
    u16* plane = (qk == 0) ? qp : (qk == 1) ? kp : vp;
    // freqs[h][t] = pi * 10^((t*8+h)/128), t = m
    float fr = 3.14159265358979323846f * expf((float)(m * 8 + h) * (2.302585092994046f / 128.f));
    #pragma unroll
    for (int ri = 0; ri < 2; ri++)
    #pragma unroll
    for (int reg = 0; reg < 4; reg++) {
        int rl = wm * 32 + ri * 16 + quad * 4 + reg;
        int p = bm + rl;
        size_t basep = ((size_t)((p >> 10) * 8 + h) * 1024 + (p & 1023)) * 64;
        float v0 = acc[ri][0][reg], v1 = acc[ri][1][reg];
        if (qk < 2) {
            float ivn = invn[ri][reg];
            v0 *= ivn; v1 *= ivn;
            if (wn == 0) {   // dims 0..31: rotate (d, d+16)
                float th = pos[p] * fr;
                float cs = cosf(th), sn = sinf(th);
                float o0 = v0 * cs - v1 * sn;
                float o1 = v1 * cs + v0 * sn;
                v0 = o0; v1 = o1;
            }
        }
        plane[basep + wn * 32 + m]      = f2bf(v0);
        plane[basep + wn * 32 + 16 + m] = f2bf(v1);
    }
}

// ---------------- K5: MFMA GEMM (out proj), BK=128 quad-staged: C fp32 = A @ B^T + skip
__global__ __launch_bounds__(256) void gemm_out(
    const u16* __restrict__ A, const u16* __restrict__ B,
    float* __restrict__ C, const float* __restrict__ skip, int N, int K)
{
    __shared__ __align__(16) u16 As[4][64][40];
    __shared__ __align__(16) u16 Bs[4][64][40];
    int tid = threadIdx.x;
    int lane = tid & 63;
    int w = tid >> 6;
    int wm = w >> 1, wn = w & 1;
    int bm = blockIdx.x * 64, bn = blockIdx.y * 64;
    int lrow = tid >> 2, lc8 = (tid & 3) * 8;

    f32x4 zero = {0.f, 0.f, 0.f, 0.f};
    f32x4 acc[2][2];
    acc[0][0] = zero; acc[0][1] = zero; acc[1][0] = zero; acc[1][1] = zero;

    const u16* Ap = A + (size_t)(bm + lrow) * K + lc8;
    const u16* Bp = B + (size_t)(bn + lrow) * K + lc8;
    int r = lane & 15, kq = (lane >> 4) * 8;

    for (int k0 = 0; k0 < K; k0 += 128) {
        #pragma unroll
        for (int s = 0; s < 4; s++) {
            *(uint4*)&As[s][lrow][lc8] = *(const uint4*)(Ap + k0 + s * 32);
            *(uint4*)&Bs[s][lrow][lc8] = *(const uint4*)(Bp + k0 + s * 32);
        }
        __syncthreads();
        #pragma unroll
        for (int kk = 0; kk < 4; kk++)
        #pragma unroll
        for (int ri = 0; ri < 2; ri++) {
            bf16x8 af = *(const bf16x8*)&As[kk][wm * 32 + ri * 16 + r][kq];
            #pragma unroll
            for (int ci = 0; ci < 2; ci++) {
                bf16x8 bfr = *(const bf16x8*)&Bs[kk][wn * 32 + ci * 16 + r][kq];
                acc[ri][ci] = __builtin_amdgcn_mfma_f32_16x16x32_bf16(af, bfr, acc[ri][ci], 0, 0, 0);
            }
        }
        __syncthreads();
    }

    #pragma unroll
    for (int ri = 0; ri < 2; ri++)
    #pragma unroll
    for (int ci = 0; ci < 2; ci++) {
        int col = bn + wn * 32 + ci * 16 + (lane & 15);
        int row0 = bm + wm * 32 + ri * 16 + (lane >> 4) * 4;
        #pragma unroll
        for (int reg = 0; reg < 4; reg++) {
            size_t idx = (size_t)(row0 + reg) * N + col;
            C[idx] = acc[ri][ci][reg] + skip[idx];
        }
    }
}

// ---------------- K4: MFMA neighborhood attention.
// One block per (n, h, 8x8 query tile). Union of neighborhoods = 14x14 = 196 keys.
__global__ __launch_bounds__(256) void attn_mfma(
    const u16* __restrict__ qp, const u16* __restrict__ kp, const u16* __restrict__ vp,
    u16* __restrict__ ob)
{
    __shared__ __align__(16) u16 Kb[208 * 72];   // K:[nb][64] stride 72; reused as Vt:[64][224] stride 234
    __shared__ __align__(16) u16 Sb[64 * 232];   // S fp16 then P bf16, row stride 232

    int tid = threadIdx.x, lane = tid & 63, w = tid >> 6;
    int bx = blockIdx.x;
    int n = bx >> 7, h = (bx >> 4) & 7, t = bx & 15;
    int ti = (t >> 2) * 8, tj = (t & 3) * 8;
    int r0 = min(max(ti - 3, 0), 18), c0 = min(max(tj - 3, 0), 18);
    const u16* qpl = qp + ((size_t)(n * 8 + h) << 16);
    const u16* kpl = kp + ((size_t)(n * 8 + h) << 16);
    const u16* vpl = vp + ((size_t)(n * 8 + h) << 16);

    for (int g = tid; g < 1568; g += 256) {
        int nb = g >> 3, k8 = (g & 7) << 3;
        int ar = nb / 14, ac = nb - ar * 14;
        *(uint4*)&Kb[nb * 72 + k8] =
            *(const uint4*)&kpl[(size_t)((r0 + ar) * 32 + c0 + ac) * 64 + k8];
    }
    __syncthreads();

    int m = lane & 15, quad = lane >> 4;
    {
        int r = w * 16 + m;
        int tok = (ti + (r >> 3)) * 32 + (tj + (r & 7));
        bf16x8 qf0 = *(const bf16x8*)&qpl[(size_t)tok * 64 + quad * 8];
        bf16x8 qf1 = *(const bf16x8*)&qpl[(size_t)tok * 64 + 32 + quad * 8];
        _Float16* sp = (_Float16*)Sb;
        #pragma unroll
        for (int nt = 0; nt < 13; nt++) {
            f32x4 acc = {0.f, 0.f, 0.f, 0.f};
            bf16x8 b0 = *(const bf16x8*)&Kb[(nt * 16 + m) * 72 + quad * 8];
            bf16x8 b1 = *(const bf16x8*)&Kb[(nt * 16 + m) * 72 + 32 + quad * 8];
            acc = __builtin_amdgcn_mfma_f32_16x16x32_bf16(qf0, b0, acc, 0, 0, 0);
            acc = __builtin_amdgcn_mfma_f32_16x16x32_bf16(qf1, b1, acc, 0, 0, 0);
            #pragma unroll
            for (int reg = 0; reg < 4; reg++)
                sp[(w * 16 + quad * 4 + reg) * 232 + nt * 16 + m] = (_Float16)acc[reg];
        }
    }
    __syncthreads();

    for (int g = tid; g < 1568; g += 256) {
        int nb = g >> 3, k8 = (g & 7) << 3;
        int ar = nb / 14, ac = nb - ar * 14;
        uint4 v4 = *(const uint4*)&vpl[(size_t)((r0 + ar) * 32 + c0 + ac) * 64 + k8];
        u32 uu[4] = {v4.x, v4.y, v4.z, v4.w};
        #pragma unroll
        for (int e = 0; e < 4; e++) {
            Kb[(k8 + 2 * e) * 234 + nb]     = (u16)(uu[e] & 0xffff);
            Kb[(k8 + 2 * e + 1) * 234 + nb] = (u16)(uu[e] >> 16);
        }
    }
    for (int g = tid; g < 1792; g += 256) {
        int d = g / 28, nb = 196 + (g - d * 28);
        Kb[d * 234 + nb] = 0;
    }

    {
        int l16 = lane & 15, g4 = lane >> 4;
        #pragma unroll
        for (int it = 0; it < 4; it++) {
            int rr = w * 16 + it * 4 + g4;
            int i2 = ti + (rr >> 3), j2 = tj + (rr & 7);
            int alo = min(max(i2 - 3, 0), 25) - r0;
            int blo = min(max(j2 - 3, 0), 25) - c0;
            const _Float16* sp = (const _Float16*)&Sb[rr * 232];
            float vals[14];
            float mx = -1e30f;
            #pragma unroll
            for (int c = 0; c < 14; c++) {
                int col = l16 + c * 16;
                float v = -1e30f;
                if (col < 196) {
                    int ar = col / 14, ac = col - ar * 14;
                    if (ar >= alo && ar < alo + 7 && ac >= blo && ac < blo + 7)
                        v = (float)sp[col];
                }
                vals[c] = v; mx = fmaxf(mx, v);
            }
            #pragma unroll
            for (int d = 1; d < 16; d <<= 1) mx = fmaxf(mx, __shfl_xor(mx, d));
            float s = 0.f;
            #pragma unroll
            for (int c = 0; c < 14; c++) {
                float e = (vals[c] > -1e29f) ? expf(vals[c] - mx) : 0.f;
                vals[c] = e; s += e;
            }
            #pragma unroll
            for (int d = 1; d < 16; d <<= 1) s += __shfl_xor(s, d);
            float rs = __frcp_rn(s);
            u16* pp = &Sb[rr * 232];
            #pragma unroll
            for (int c = 0; c < 14; c++)
                pp[l16 + c * 16] = f2bf(vals[c] * rs);
        }
    }
    __syncthreads();

    f32x4 oacc[4];
    #pragma unroll
    for (int nt = 0; nt < 4; nt++) { f32x4 z = {0.f,0.f,0.f,0.f}; oacc[nt] = z; }
    #pragma unroll
    for (int ks = 0; ks < 7; ks++) {
        bf16x8 pa = *(const bf16x8*)&Sb[(w * 16 + m) * 232 + ks * 32 + quad * 8];
        #pragma unroll
        for (int nt = 0; nt < 4; nt++) {
            int ad = (nt * 16 + m) * 234 + ks * 32 + quad * 8;
            union { u32 u[4]; bf16x8 v; } vb;
            vb.u[0] = *(const u32*)&Kb[ad];
            vb.u[1] = *(const u32*)&Kb[ad + 2];
            vb.u[2] = *(const u32*)&Kb[ad + 4];
            vb.u[3] = *(const u32*)&Kb[ad + 6];
            oacc[nt] = __builtin_amdgcn_mfma_f32_16x16x32_bf16(pa, vb.v, oacc[nt], 0, 0, 0);
        }
    }
    #pragma unroll
    for (int nt = 0; nt < 4; nt++) {
        #pragma unroll
        for (int reg = 0; reg < 4; reg++) {
            int rr = w * 16 + quad * 4 + reg;
            int tok = (ti + (rr >> 3)) * 32 + (tj + (rr & 7));
            ob[(size_t)(n * 1024 + tok) * 512 + h * 64 + nt * 16 + m] = f2bf(oacc[nt][reg]);
        }
    }
}

extern "C" void kernel_launch(void* const* d_in, const int* in_sizes, int n_in,
                              void* d_out, int out_size, void* d_ws, size_t ws_size,
                              hipStream_t stream)
{
    // Match inputs by unique element count (robust to ordering).
    const float *x = nullptr, *pos = nullptr, *cond = nullptr, *w_cond = nullptr,
                *w_qkv = nullptr, *scale = nullptr, *w_out = nullptr;
    for (int i = 0; i < n_in; i++) {
        switch (in_sizes[i]) {
            case 1048576: x      = (const float*)d_in[i]; break;  // 2*32*32*512
            case 2048:    pos    = (const float*)d_in[i]; break;  // 2*32*32*1
            case 1536:    cond   = (const float*)d_in[i]; break;  // 2*768
            case 393216:  w_cond = (const float*)d_in[i]; break;  // 512*768
            case 786432:  w_qkv  = (const float*)d_in[i]; break;  // 1536*512
            case 8:       scale  = (const float*)d_in[i]; break;  // 8
            case 262144:  w_out  = (const float*)d_in[i]; break;  // 512*512
            default: break;
        }
    }
    float* out = (float*)d_out;   // FLOAT32 output

    // ws: ns 4K | wqkvb 1.5M | woutb .5M | xn 2M | qp/kp/vp 2M each | ob 2M
    char* ws = (char*)d_ws;
    float* ns    = (float*)ws;                          // [2][512]
    u16*   wqkvb = (u16*)(ws + 12288);                  // [1536][512]  bf16
    u16*   woutb = (u16*)(ws + 12288 + 1572864);        // [512][512]   bf16
    u16*   xn    = (u16*)(ws + 12288 + 2097152);        // [2048][512]  bf16
    u16*   qp    = (u16*)(ws + 12288 + 4194304);        // [2][8][1024][64] bf16
    u16*   kp    = (u16*)(ws + 12288 + 6291456);        // same
    u16*   vp    = (u16*)(ws + 12288 + 8388608);        // same
    u16*   ob    = (u16*)(ws + 12288 + 10485760);       // [2048][512]  bf16

    cond_kernel<<<256, 256, 0, stream>>>(cond, w_cond, ns);
    prep_kernel<<<1536, 256, 0, stream>>>(x, ns, w_qkv, w_out, xn, wqkvb, woutb);
    gemm_qkv<<<dim3(32, 24), 256, 0, stream>>>(xn, wqkvb, pos, scale, qp, kp, vp);
    attn_mfma<<<256, 256, 0, stream>>>(qp, kp, vp, ob);
    gemm_out<<<dim3(32, 8), 256, 0, stream>>>(ob, woutb, out, x, 512, 512);
}